// Round 1
// baseline (5606.528 us; speedup 1.0000x reference)
//
#include <hip/hip_runtime.h>
#include <math.h>

#define PI_F 3.14159265358979323846f

#define NS   4
#define CIN  64
#define HH   128
#define WW   128
#define KXN  65          // rfft last-axis size
#define NPIX (HH*WW)
#define MMAT 1600        // CIN*5*5
#define NBK  25          // MMAT/64

// float offsets in workspace (total 11,937,536 floats = 47.75 MB)
#define OFF_SINV 0
#define OFF_E    33280
#define OFF_ER   98816
#define OFF_EW   165376
#define OFF_VR   231936
#define OFF_WB   298496
#define OFF_R    364032
#define OFF_Q    1691136
#define OFF_PM   11931136

// ---------------------------------------------------------------------------
// Sinv[n,ky,kx] = 1 / (sum_c |D_c(ky,kx)|^2 + alpha_x/64); D from 5x5 psf DFT
// ---------------------------------------------------------------------------
__global__ __launch_bounds__(256) void k_sinv(const float* __restrict__ dict,
                                              const float* __restrict__ alpha_x,
                                              float* __restrict__ ws) {
  int idx = blockIdx.x * 256 + threadIdx.x;
  int n = blockIdx.y;
  if (idx >= HH * KXN) return;
  int ky = idx / KXN, kx = idx % KXN;
  float tr[25], ti[25];
  {
    float eyr[5], eyi[5], exr[5], exi[5];
#pragma unroll
    for (int a = 0; a < 5; ++a) {
      float s, c;
      sincosf(-2.0f * PI_F * (float)(ky * (a - 2)) / 128.0f, &s, &c);
      eyr[a] = c; eyi[a] = s;
      sincosf(-2.0f * PI_F * (float)(kx * (a - 2)) / 128.0f, &s, &c);
      exr[a] = c; exi[a] = s;
    }
#pragma unroll
    for (int a = 0; a < 5; ++a)
#pragma unroll
      for (int b = 0; b < 5; ++b) {
        tr[a*5+b] = eyr[a]*exr[b] - eyi[a]*exi[b];
        ti[a*5+b] = eyr[a]*exi[b] + eyi[a]*exr[b];
      }
  }
  const float* dn = dict + n * CIN * 25;
  float S = 0.0f;
  for (int c = 0; c < CIN; ++c) {
    const float* p = dn + c * 25;
    float Dr = 0.0f, Di = 0.0f;
#pragma unroll
    for (int t = 0; t < 25; ++t) { Dr += p[t]*tr[t]; Di += p[t]*ti[t]; }
    S += Dr*Dr + Di*Di;
  }
  float a = alpha_x[n] * (1.0f/64.0f);
  ws[OFF_SINV + (n*HH + ky)*KXN + kx] = 1.0f / (S + a);
}

// ---------------------------------------------------------------------------
// e[n,p] = y[n,p] - sum_c sum_{a,b} psf[n,c,a,b] * x[n,c,(ph+a-2)%128,(pw+b-2)%128]
// block: (tile of 16x16 px, n); circular indexing
// ---------------------------------------------------------------------------
__global__ __launch_bounds__(256) void k_e(const float* __restrict__ x,
                                           const float* __restrict__ dict,
                                           const float* __restrict__ y,
                                           float* __restrict__ ws) {
  __shared__ float psf_s[CIN*25];
  __shared__ float xt[20*20];
  int n = blockIdx.y, tile = blockIdx.x, tid = threadIdx.x;
  int h0 = (tile >> 3) * 16, w0 = (tile & 7) * 16;
  for (int i = tid; i < CIN*25; i += 256) psf_s[i] = dict[n*CIN*25 + i];
  int py = tid >> 4, px = tid & 15;
  float acc = 0.0f;
  for (int c = 0; c < CIN; ++c) {
    __syncthreads();
    for (int i = tid; i < 400; i += 256) {
      int r = i / 20, cc = i % 20;
      int gh = (h0 + r - 2) & 127, gw = (w0 + cc - 2) & 127;
      xt[i] = x[((n*CIN + c)*HH + gh)*WW + gw];
    }
    __syncthreads();
    const float* pp = psf_s + c*25;
#pragma unroll
    for (int a = 0; a < 5; ++a)
#pragma unroll
      for (int b = 0; b < 5; ++b)
        acc += pp[a*5+b] * xt[(py+a)*20 + (px+b)];
  }
  int h = h0+py, w = w0+px;
  ws[OFF_E + (n*HH + h)*WW + w] = y[(n*HH + h)*WW + w] - acc;
}

// ---------------------------------------------------------------------------
// tiny table-DFT kernels (only 4 images each way)
// tw[t] = cis(-2*pi*t/128)
// ---------------------------------------------------------------------------
__global__ __launch_bounds__(256) void k_fft_rows(float* __restrict__ ws) {
  __shared__ float twr[128], twi[128];
  int tid = threadIdx.x;
  if (tid < 128) { float s, c; sincosf(-2.0f*PI_F*(float)tid/128.0f, &s, &c); twr[tid]=c; twi[tid]=s; }
  __syncthreads();
  int idx = blockIdx.x*256 + tid, n = blockIdx.y;
  if (idx >= HH*KXN) return;
  int h = idx / KXN, k = idx % KXN;
  const float* row = ws + OFF_E + (n*HH + h)*WW;
  float sr = 0, si = 0;
  for (int w = 0; w < 128; ++w) {
    int t = (w*k) & 127;
    float v = row[w];
    sr += v*twr[t]; si += v*twi[t];
  }
  float* o = ws + OFF_ER + ((n*HH + h)*KXN + k)*2;
  o[0] = sr; o[1] = si;
}

__global__ __launch_bounds__(256) void k_fft_cols(float* __restrict__ ws) {
  __shared__ float twr[128], twi[128];
  int tid = threadIdx.x;
  if (tid < 128) { float s, c; sincosf(-2.0f*PI_F*(float)tid/128.0f, &s, &c); twr[tid]=c; twi[tid]=s; }
  __syncthreads();
  int idx = blockIdx.x*256 + tid, n = blockIdx.y;
  if (idx >= HH*KXN) return;
  int ky = idx / KXN, kx = idx % KXN;
  const float* Er = ws + OFF_ER + (size_t)n*HH*KXN*2;
  float sr = 0, si = 0;
  for (int h = 0; h < 128; ++h) {
    int t = (h*ky) & 127;
    float ar = Er[(h*KXN + kx)*2], ai = Er[(h*KXN + kx)*2 + 1];
    sr += ar*twr[t] - ai*twi[t];
    si += ar*twi[t] + ai*twr[t];
  }
  float sv = ws[OFF_SINV + (n*HH + ky)*KXN + kx];
  float* o = ws + OFF_EW + ((n*HH + ky)*KXN + kx)*2;
  o[0] = sr*sv; o[1] = si*sv;
}

__global__ __launch_bounds__(256) void k_ifft_cols(float* __restrict__ ws) {
  __shared__ float twr[128], twi[128];
  int tid = threadIdx.x;
  if (tid < 128) { float s, c; sincosf(-2.0f*PI_F*(float)tid/128.0f, &s, &c); twr[tid]=c; twi[tid]=s; }
  __syncthreads();
  int idx = blockIdx.x*256 + tid, n = blockIdx.y;
  if (idx >= HH*KXN) return;
  int h = idx / KXN, kx = idx % KXN;
  const float* EW = ws + OFF_EW + (size_t)n*HH*KXN*2;
  float sr = 0, si = 0;
  for (int ky = 0; ky < 128; ++ky) {
    int t = (h*ky) & 127;
    float ar = EW[(ky*KXN + kx)*2], ai = EW[(ky*KXN + kx)*2 + 1];
    // multiply by cis(+theta) = (twr, -twi)
    sr += ar*twr[t] + ai*twi[t];
    si += ai*twr[t] - ar*twi[t];
  }
  float* o = ws + OFF_VR + ((n*HH + h)*KXN + kx)*2;
  o[0] = sr; o[1] = si;
}

__global__ __launch_bounds__(256) void k_ifft_rows(float* __restrict__ ws) {
  __shared__ float twr[128], twi[128];
  int tid = threadIdx.x;
  if (tid < 128) { float s, c; sincosf(-2.0f*PI_F*(float)tid/128.0f, &s, &c); twr[tid]=c; twi[tid]=s; }
  __syncthreads();
  int idx = blockIdx.x*256 + tid, n = blockIdx.y;
  int h = idx >> 7, w = idx & 127;
  const float* Vr = ws + OFF_VR + (size_t)n*HH*KXN*2;
  float s = 0.0f;
  for (int kx = 0; kx <= 64; ++kx) {
    int t = (w*kx) & 127;
    float ar = Vr[(h*KXN + kx)*2], ai = Vr[(h*KXN + kx)*2 + 1];
    float re = ar*twr[t] + ai*twi[t];   // Re(V * cis(+theta))
    s += (kx == 0 || kx == 64) ? re : 2.0f*re;
  }
  ws[OFF_WB + (n*HH + h)*WW + w] = s * (1.0f/16384.0f);
}

// ---------------------------------------------------------------------------
// x_new[n,c,p] = x[n,c,p] + sum_{a,b} psf[n,c,a,b]*wbuf[n,(ph-a+2)%128,(pw-b+2)%128]
// ---------------------------------------------------------------------------
__global__ __launch_bounds__(256) void k_xnew(const float* __restrict__ x,
                                              const float* __restrict__ dict,
                                              const float* __restrict__ ws,
                                              float* __restrict__ out) {
  __shared__ float psf_s[CIN*25];
  __shared__ float wt[20*20];
  int n = blockIdx.y, tile = blockIdx.x, tid = threadIdx.x;
  int h0 = (tile >> 3) * 16, w0 = (tile & 7) * 16;
  for (int i = tid; i < CIN*25; i += 256) psf_s[i] = dict[n*CIN*25 + i];
  for (int i = tid; i < 400; i += 256) {
    int r = i / 20, cc = i % 20;
    int gh = (h0 + r - 2) & 127, gw = (w0 + cc - 2) & 127;
    wt[i] = ws[OFF_WB + (n*HH + gh)*WW + gw];
  }
  __syncthreads();
  int py = tid >> 4, px = tid & 15;
  int h = h0+py, w = w0+px;
  for (int c = 0; c < CIN; ++c) {
    float acc = 0.0f;
    const float* pp = psf_s + c*25;
#pragma unroll
    for (int a = 0; a < 5; ++a)
#pragma unroll
      for (int b = 0; b < 5; ++b)
        acc += pp[a*5+b] * wt[(py + 4 - a)*20 + (px + 4 - b)];
    int gi = ((n*CIN + c)*HH + h)*WW + w;
    out[gi] = x[gi] + acc;
  }
}

// ---------------------------------------------------------------------------
// R[n,i,j,u,v] = sum_{h,w} xnew_i[h+u-4, w+v-4] * xnew_j[h,w]  (zero-pad)
// one block per (pair p -> (i>=j), n); symmetric fill R[j,i,80-t]
// ---------------------------------------------------------------------------
__global__ __launch_bounds__(256) void k_corr(const float* __restrict__ xn,
                                              float* __restrict__ ws) {
  __shared__ float xi_s[72*136];
  __shared__ float red_s[4][81];
  int n = blockIdx.y, p = blockIdx.x, tid = threadIdx.x;
  int ii = 0;
  while ((ii+1)*(ii+2)/2 <= p) ++ii;
  int jj = p - ii*(ii+1)/2;
  const float* Xi = xn + (size_t)(n*CIN + ii)*NPIX;
  const float* Xj = xn + (size_t)(n*CIN + jj)*NPIX;
  float acc[81];
#pragma unroll
  for (int t = 0; t < 81; ++t) acc[t] = 0.0f;

  for (int hh = 0; hh < 2; ++hh) {
    __syncthreads();
    for (int t = tid; t < 72*136; t += 256) {
      int r = t / 136, cc = t % 136;
      int gh = hh*64 - 4 + r, gw = cc - 4;
      float v = 0.0f;
      if (gh >= 0 && gh < 128 && gw >= 0 && gw < 128) v = Xi[gh*128 + gw];
      xi_s[t] = v;
    }
    __syncthreads();
    for (int s = 0; s < 4; ++s) {
      int seg = tid + 256*s;            // 0..1023
      int hloc = seg >> 4;              // 0..63
      int w0 = (seg & 15) << 3;         // 0..120
      const float* xjr = Xj + (hh*64 + hloc)*128 + w0;
      float xj0[8];
      {
        const float4 t0 = *reinterpret_cast<const float4*>(xjr);
        const float4 t1 = *reinterpret_cast<const float4*>(xjr + 4);
        xj0[0]=t0.x; xj0[1]=t0.y; xj0[2]=t0.z; xj0[3]=t0.w;
        xj0[4]=t1.x; xj0[5]=t1.y; xj0[6]=t1.z; xj0[7]=t1.w;
      }
#pragma unroll
      for (int u = 0; u < 9; ++u) {
        const float* rowp = &xi_s[(hloc + u)*136 + w0];
        float xv[16];
        const float4 a0 = *reinterpret_cast<const float4*>(rowp + 0);
        const float4 a1 = *reinterpret_cast<const float4*>(rowp + 4);
        const float4 a2 = *reinterpret_cast<const float4*>(rowp + 8);
        const float4 a3 = *reinterpret_cast<const float4*>(rowp + 12);
        xv[0]=a0.x; xv[1]=a0.y; xv[2]=a0.z; xv[3]=a0.w;
        xv[4]=a1.x; xv[5]=a1.y; xv[6]=a1.z; xv[7]=a1.w;
        xv[8]=a2.x; xv[9]=a2.y; xv[10]=a2.z; xv[11]=a2.w;
        xv[12]=a3.x; xv[13]=a3.y; xv[14]=a3.z; xv[15]=a3.w;
#pragma unroll
        for (int v = 0; v < 9; ++v)
#pragma unroll
          for (int kk = 0; kk < 8; ++kk)
            acc[u*9+v] += xv[v+kk] * xj0[kk];
      }
    }
  }
  int lane = tid & 63, wv = tid >> 6;
#pragma unroll
  for (int t = 0; t < 81; ++t) {
    float v = acc[t];
    v += __shfl_down(v, 32);
    v += __shfl_down(v, 16);
    v += __shfl_down(v, 8);
    v += __shfl_down(v, 4);
    v += __shfl_down(v, 2);
    v += __shfl_down(v, 1);
    if (lane == 0) red_s[wv][t] = v;
  }
  __syncthreads();
  if (tid < 81) {
    float s = red_s[0][tid] + red_s[1][tid] + red_s[2][tid] + red_s[3][tid];
    float* Rp = ws + OFF_R;
    Rp[((n*CIN + ii)*CIN + jj)*81 + tid] = s;
    Rp[((n*CIN + jj)*CIN + ii)*81 + (80 - tid)] = s;
  }
}

// ---------------------------------------------------------------------------
// Q[n,m1=(j,a,c), m2=(i,b,d)] = R[n,i,j,4+b-a,4+d-c] + (m1==m2)*a_d
// ---------------------------------------------------------------------------
__global__ __launch_bounds__(256) void k_build_q(const float* __restrict__ Rp,
                                                 const float* __restrict__ alpha_d,
                                                 const float* __restrict__ regp,
                                                 float* __restrict__ Q) {
  int idx = blockIdx.x*256 + threadIdx.x;      // < 10,240,000
  int m2 = idx % MMAT;
  int t  = idx / MMAT;
  int m1 = t % MMAT;
  int n  = t / MMAT;
  int i = m2 / 25, r2 = m2 % 25, b = r2 / 5, d = r2 % 5;
  int j = m1 / 25, r1 = m1 % 25, a = r1 / 5, c = r1 % 5;
  float v = Rp[((n*CIN + i)*CIN + j)*81 + (4 + b - a)*9 + (4 + d - c)];
  if (m1 == m2) v += alpha_d[n] * 16384.0f * regp[0] * (1.0f/1600.0f);
  Q[idx] = v;
}

// ---------------------------------------------------------------------------
// Pm[n, i*25+u*5+v] = sum_{h,w} xnew[n,i,h+u-2,w+v-2]*y[n,h,w] + a_d*d[n,0,i,u,v]
// block per (i, n); zero-pad
// ---------------------------------------------------------------------------
__global__ __launch_bounds__(256) void k_pm(const float* __restrict__ xn,
                                            const float* __restrict__ y,
                                            const float* __restrict__ dict,
                                            const float* __restrict__ alpha_d,
                                            const float* __restrict__ regp,
                                            float* __restrict__ ws) {
  __shared__ float xt[20*20];
  __shared__ float red_s[4][25];
  int n = blockIdx.y, i = blockIdx.x, tid = threadIdx.x;
  int py = tid >> 4, px = tid & 15;
  float acc[25];
#pragma unroll
  for (int t = 0; t < 25; ++t) acc[t] = 0.0f;
  const float* Xi = xn + (size_t)(n*CIN + i)*NPIX;
  for (int tile = 0; tile < 64; ++tile) {
    int h0 = (tile >> 3)*16, w0 = (tile & 7)*16;
    __syncthreads();
    for (int t = tid; t < 400; t += 256) {
      int r = t / 20, cc = t % 20;
      int gh = h0 + r - 2, gw = w0 + cc - 2;
      float v = 0.0f;
      if (gh >= 0 && gh < 128 && gw >= 0 && gw < 128) v = Xi[gh*128 + gw];
      xt[t] = v;
    }
    __syncthreads();
    float yv = y[(n*HH + h0 + py)*WW + w0 + px];
#pragma unroll
    for (int u = 0; u < 5; ++u)
#pragma unroll
      for (int v = 0; v < 5; ++v)
        acc[u*5+v] += xt[(py+u)*20 + (px+v)] * yv;
  }
  int lane = tid & 63, wv = tid >> 6;
#pragma unroll
  for (int t = 0; t < 25; ++t) {
    float v = acc[t];
    v += __shfl_down(v, 32);
    v += __shfl_down(v, 16);
    v += __shfl_down(v, 8);
    v += __shfl_down(v, 4);
    v += __shfl_down(v, 2);
    v += __shfl_down(v, 1);
    if (lane == 0) red_s[wv][t] = v;
  }
  __syncthreads();
  if (tid < 25) {
    float s = red_s[0][tid] + red_s[1][tid] + red_s[2][tid] + red_s[3][tid];
    float ad = alpha_d[n] * 16384.0f * regp[0] * (1.0f/1600.0f);
    ws[OFF_PM + n*MMAT + i*25 + tid] = s + ad * dict[(n*CIN + i)*25 + tid];
  }
}

// ---------------------------------------------------------------------------
// Blocked Cholesky (nb=64, right-looking), in-place lower triangle of Q
// ---------------------------------------------------------------------------
__global__ __launch_bounds__(64) void k_chol_diag(float* __restrict__ Q, int k) {
  __shared__ float La[64*65];
  int n = blockIdx.x, tid = threadIdx.x;
  float* Qn = Q + (size_t)n*MMAT*MMAT;
  int g0 = k*64;
  for (int c = 0; c < 64; ++c) La[tid*65+c] = Qn[(size_t)(g0+tid)*MMAT + g0 + c];
  __syncthreads();
  for (int j = 0; j < 64; ++j) {
    if (tid == j) {
      float s = La[j*65+j];
      for (int t = 0; t < j; ++t) s -= La[j*65+t]*La[j*65+t];
      La[j*65+j] = sqrtf(fmaxf(s, 1e-20f));
    }
    __syncthreads();
    if (tid > j) {
      float s = La[tid*65+j];
      for (int t = 0; t < j; ++t) s -= La[tid*65+t]*La[j*65+t];
      La[tid*65+j] = s / La[j*65+j];
    }
    __syncthreads();
  }
  for (int c = 0; c < 64; ++c) Qn[(size_t)(g0+tid)*MMAT + g0 + c] = La[tid*65+c];
}

__global__ __launch_bounds__(64) void k_chol_panel(float* __restrict__ Q, int k) {
  __shared__ float Lk[64*65];
  __shared__ float V[64*65];
  int n = blockIdx.y, tid = threadIdx.x;
  float* Qn = Q + (size_t)n*MMAT*MMAT;
  int k0 = k*64;
  int gr0 = k0 + 64 + blockIdx.x*64;
  for (int c = 0; c < 64; ++c) {
    Lk[tid*65+c] = Qn[(size_t)(k0+tid)*MMAT + k0 + c];
    V[tid*65+c]  = Qn[(size_t)(gr0+tid)*MMAT + k0 + c];
  }
  __syncthreads();
  // independent per-row forward substitution
  for (int j = 0; j < 64; ++j) {
    float s = V[tid*65+j];
    for (int t = 0; t < j; ++t) s -= V[tid*65+t]*Lk[j*65+t];
    V[tid*65+j] = s / Lk[j*65+j];
  }
  for (int c = 0; c < 64; ++c) Qn[(size_t)(gr0+tid)*MMAT + k0 + c] = V[tid*65+c];
}

__global__ __launch_bounds__(256) void k_chol_update(float* __restrict__ Q, int k) {
  __shared__ float As[64*68];
  __shared__ float Bs[64*68];
  int n = blockIdx.y, tid = threadIdx.x;
  float* Qn = Q + (size_t)n*MMAT*MMAT;
  int k0 = k*64, t0 = k0 + 64;
  int b = blockIdx.x;
  int ti = 0;
  while (((ti+1)*(ti+2))/2 <= b) ++ti;
  int tj = b - (ti*(ti+1))/2;
  int gr0 = t0 + ti*64, gc0 = t0 + tj*64;
  for (int idx = tid; idx < 4096; idx += 256) {
    int kk = idx & 63, r = idx >> 6;
    As[kk*68 + r] = Qn[(size_t)(gr0+r)*MMAT + k0 + kk];
    Bs[kk*68 + r] = Qn[(size_t)(gc0+r)*MMAT + k0 + kk];
  }
  __syncthreads();
  int tx = tid & 15, ty = tid >> 4;
  float accm[4][4];
#pragma unroll
  for (int r = 0; r < 4; ++r)
#pragma unroll
    for (int c = 0; c < 4; ++c) accm[r][c] = 0.0f;
  for (int kk = 0; kk < 64; ++kk) {
    const float4 av = *reinterpret_cast<const float4*>(&As[kk*68 + ty*4]);
    const float4 bv = *reinterpret_cast<const float4*>(&Bs[kk*68 + tx*4]);
    float ar[4] = {av.x, av.y, av.z, av.w};
    float br[4] = {bv.x, bv.y, bv.z, bv.w};
#pragma unroll
    for (int r = 0; r < 4; ++r)
#pragma unroll
      for (int c = 0; c < 4; ++c) accm[r][c] += ar[r]*br[c];
  }
#pragma unroll
  for (int r = 0; r < 4; ++r) {
    int gr = gr0 + ty*4 + r;
    float* qp = &Qn[(size_t)gr*MMAT + gc0 + tx*4];
    float4 cv = *reinterpret_cast<float4*>(qp);
    cv.x -= accm[r][0]; cv.y -= accm[r][1]; cv.z -= accm[r][2]; cv.w -= accm[r][3];
    *reinterpret_cast<float4*>(qp) = cv;
  }
}

// ---------------------------------------------------------------------------
// Blocked forward+backward triangular solve, one block per sample; writes d_new
// ---------------------------------------------------------------------------
__global__ __launch_bounds__(256) void k_trsv(const float* __restrict__ Q,
                                              const float* __restrict__ Pm,
                                              float* __restrict__ out) {
  __shared__ float rhs[MMAT];
  __shared__ float Lk[64*65];
  int n = blockIdx.x, tid = threadIdx.x;
  const float* Qn = Q + (size_t)n*MMAT*MMAT;
  for (int i = tid; i < MMAT; i += 256) rhs[i] = Pm[n*MMAT + i];
  __syncthreads();
  // forward: L z = p
  for (int kb = 0; kb < NBK; ++kb) {
    int g0 = kb*64;
    for (int idx = tid; idx < 4096; idx += 256) {
      int r = idx >> 6, c = idx & 63;
      Lk[r*65+c] = Qn[(size_t)(g0+r)*MMAT + g0 + c];
    }
    __syncthreads();
    if (tid < 64) {
      float v = rhs[g0 + tid];
      for (int j = 0; j < 64; ++j) {
        if (tid == j) v = v / Lk[j*65+j];
        float zj = __shfl(v, j);
        if (tid > j) v -= Lk[tid*65+j]*zj;
      }
      rhs[g0+tid] = v;
    }
    __syncthreads();
    for (int i = g0 + 64 + tid; i < MMAT; i += 256) {
      float v = rhs[i];
      const float4* r4 = reinterpret_cast<const float4*>(&Qn[(size_t)i*MMAT + g0]);
#pragma unroll
      for (int j4 = 0; j4 < 16; ++j4) {
        float4 q = r4[j4];
        v -= q.x*rhs[g0+4*j4] + q.y*rhs[g0+4*j4+1] + q.z*rhs[g0+4*j4+2] + q.w*rhs[g0+4*j4+3];
      }
      rhs[i] = v;
    }
    __syncthreads();
  }
  // backward: L^T x = z
  for (int kb = NBK-1; kb >= 0; --kb) {
    int g0 = kb*64;
    for (int idx = tid; idx < 4096; idx += 256) {
      int r = idx >> 6, c = idx & 63;
      Lk[r*65+c] = Qn[(size_t)(g0+r)*MMAT + g0 + c];
    }
    __syncthreads();
    if (tid < 64) {
      float v = rhs[g0 + tid];
      for (int j = 63; j >= 0; --j) {
        if (tid == j) v = v / Lk[j*65+j];
        float xj = __shfl(v, j);
        if (tid < j) v -= Lk[j*65+tid]*xj;
      }
      rhs[g0+tid] = v;
    }
    __syncthreads();
    for (int i = tid; i < g0; i += 256) {
      float s = 0.0f;
      for (int j = 0; j < 64; ++j)
        s += Qn[(size_t)(g0+j)*MMAT + i] * rhs[g0+j];
      rhs[i] -= s;
    }
    __syncthreads();
  }
  for (int i = tid; i < MMAT; i += 256)
    out[4194304 + n*MMAT + i] = rhs[i];
}

// ---------------------------------------------------------------------------
extern "C" void kernel_launch(void* const* d_in, const int* in_sizes, int n_in,
                              void* d_out, int out_size, void* d_ws, size_t ws_size,
                              hipStream_t stream) {
  (void)in_sizes; (void)n_in; (void)out_size; (void)ws_size;
  const float* x    = (const float*)d_in[0];
  const float* dict = (const float*)d_in[1];
  const float* y    = (const float*)d_in[2];
  const float* ax   = (const float*)d_in[3];
  const float* ad   = (const float*)d_in[4];
  const float* regp = (const float*)d_in[5];
  float* out = (float*)d_out;
  float* ws  = (float*)d_ws;   // needs 47.75 MB

  dim3 b256(256);
  k_sinv<<<dim3(33,4), b256, 0, stream>>>(dict, ax, ws);
  k_e<<<dim3(64,4), b256, 0, stream>>>(x, dict, y, ws);
  k_fft_rows<<<dim3(33,4), b256, 0, stream>>>(ws);
  k_fft_cols<<<dim3(33,4), b256, 0, stream>>>(ws);
  k_ifft_cols<<<dim3(33,4), b256, 0, stream>>>(ws);
  k_ifft_rows<<<dim3(64,4), b256, 0, stream>>>(ws);
  k_xnew<<<dim3(64,4), b256, 0, stream>>>(x, dict, ws, out);
  k_corr<<<dim3(2080,4), b256, 0, stream>>>(out, ws);
  k_build_q<<<dim3(40000), b256, 0, stream>>>(ws + OFF_R, ad, regp, ws + OFF_Q);
  k_pm<<<dim3(64,4), b256, 0, stream>>>(out, y, dict, ad, regp, ws);

  float* Q = ws + OFF_Q;
  for (int k = 0; k < NBK; ++k) {
    k_chol_diag<<<dim3(4), dim3(64), 0, stream>>>(Q, k);
    if (k < NBK-1) {
      int nt = NBK - 1 - k;
      k_chol_panel<<<dim3(nt,4), dim3(64), 0, stream>>>(Q, k);
      k_chol_update<<<dim3(nt*(nt+1)/2,4), b256, 0, stream>>>(Q, k);
    }
  }
  k_trsv<<<dim3(4), b256, 0, stream>>>(Q, ws + OFF_PM, out);
}

// Round 2
// 4255.355 us; speedup vs baseline: 1.3175x; 1.3175x over previous
//
#include <hip/hip_runtime.h>
#include <math.h>

#define PI_F 3.14159265358979323846f

#define NS   4
#define CIN  64
#define HH   128
#define WW   128
#define KXN  65          // rfft last-axis size
#define NPIX (HH*WW)
#define MMAT 1600        // CIN*5*5
#define NBK  25          // MMAT/64

// float offsets in workspace (total 11,937,536 floats = 47.75 MB)
#define OFF_SINV 0
#define OFF_E    33280
#define OFF_ER   98816
#define OFF_EW   165376
#define OFF_VR   231936
#define OFF_WB   298496
#define OFF_R    364032
#define OFF_Q    1691136
#define OFF_PM   11931136

// ---------------------------------------------------------------------------
// Sinv[n,ky,kx] = 1 / (sum_c |D_c(ky,kx)|^2 + alpha_x/64); D from 5x5 psf DFT
// ---------------------------------------------------------------------------
__global__ __launch_bounds__(256) void k_sinv(const float* __restrict__ dict,
                                              const float* __restrict__ alpha_x,
                                              float* __restrict__ ws) {
  int idx = blockIdx.x * 256 + threadIdx.x;
  int n = blockIdx.y;
  if (idx >= HH * KXN) return;
  int ky = idx / KXN, kx = idx % KXN;
  float tr[25], ti[25];
  {
    float eyr[5], eyi[5], exr[5], exi[5];
#pragma unroll
    for (int a = 0; a < 5; ++a) {
      float s, c;
      sincosf(-2.0f * PI_F * (float)(ky * (a - 2)) / 128.0f, &s, &c);
      eyr[a] = c; eyi[a] = s;
      sincosf(-2.0f * PI_F * (float)(kx * (a - 2)) / 128.0f, &s, &c);
      exr[a] = c; exi[a] = s;
    }
#pragma unroll
    for (int a = 0; a < 5; ++a)
#pragma unroll
      for (int b = 0; b < 5; ++b) {
        tr[a*5+b] = eyr[a]*exr[b] - eyi[a]*exi[b];
        ti[a*5+b] = eyr[a]*exi[b] + eyi[a]*exr[b];
      }
  }
  const float* dn = dict + n * CIN * 25;
  float S = 0.0f;
  for (int c = 0; c < CIN; ++c) {
    const float* p = dn + c * 25;
    float Dr = 0.0f, Di = 0.0f;
#pragma unroll
    for (int t = 0; t < 25; ++t) { Dr += p[t]*tr[t]; Di += p[t]*ti[t]; }
    S += Dr*Dr + Di*Di;
  }
  float a = alpha_x[n] * (1.0f/64.0f);
  ws[OFF_SINV + (n*HH + ky)*KXN + kx] = 1.0f / (S + a);
}

// ---------------------------------------------------------------------------
// e[n,p] = y[n,p] - sum_c sum_{a,b} psf[n,c,a,b] * x[n,c,(ph+a-2)%128,(pw+b-2)%128]
// ---------------------------------------------------------------------------
__global__ __launch_bounds__(256) void k_e(const float* __restrict__ x,
                                           const float* __restrict__ dict,
                                           const float* __restrict__ y,
                                           float* __restrict__ ws) {
  __shared__ float psf_s[CIN*25];
  __shared__ float xt[20*20];
  int n = blockIdx.y, tile = blockIdx.x, tid = threadIdx.x;
  int h0 = (tile >> 3) * 16, w0 = (tile & 7) * 16;
  for (int i = tid; i < CIN*25; i += 256) psf_s[i] = dict[n*CIN*25 + i];
  int py = tid >> 4, px = tid & 15;
  float acc = 0.0f;
  for (int c = 0; c < CIN; ++c) {
    __syncthreads();
    for (int i = tid; i < 400; i += 256) {
      int r = i / 20, cc = i % 20;
      int gh = (h0 + r - 2) & 127, gw = (w0 + cc - 2) & 127;
      xt[i] = x[((n*CIN + c)*HH + gh)*WW + gw];
    }
    __syncthreads();
    const float* pp = psf_s + c*25;
#pragma unroll
    for (int a = 0; a < 5; ++a)
#pragma unroll
      for (int b = 0; b < 5; ++b)
        acc += pp[a*5+b] * xt[(py+a)*20 + (px+b)];
  }
  int h = h0+py, w = w0+px;
  ws[OFF_E + (n*HH + h)*WW + w] = y[(n*HH + h)*WW + w] - acc;
}

// ---------------------------------------------------------------------------
// tiny table-DFT kernels (only 4 images each way)
// ---------------------------------------------------------------------------
__global__ __launch_bounds__(256) void k_fft_rows(float* __restrict__ ws) {
  __shared__ float twr[128], twi[128];
  int tid = threadIdx.x;
  if (tid < 128) { float s, c; sincosf(-2.0f*PI_F*(float)tid/128.0f, &s, &c); twr[tid]=c; twi[tid]=s; }
  __syncthreads();
  int idx = blockIdx.x*256 + tid, n = blockIdx.y;
  if (idx >= HH*KXN) return;
  int h = idx / KXN, k = idx % KXN;
  const float* row = ws + OFF_E + (n*HH + h)*WW;
  float sr = 0, si = 0;
  for (int w = 0; w < 128; ++w) {
    int t = (w*k) & 127;
    float v = row[w];
    sr += v*twr[t]; si += v*twi[t];
  }
  float* o = ws + OFF_ER + ((n*HH + h)*KXN + k)*2;
  o[0] = sr; o[1] = si;
}

__global__ __launch_bounds__(256) void k_fft_cols(float* __restrict__ ws) {
  __shared__ float twr[128], twi[128];
  int tid = threadIdx.x;
  if (tid < 128) { float s, c; sincosf(-2.0f*PI_F*(float)tid/128.0f, &s, &c); twr[tid]=c; twi[tid]=s; }
  __syncthreads();
  int idx = blockIdx.x*256 + tid, n = blockIdx.y;
  if (idx >= HH*KXN) return;
  int ky = idx / KXN, kx = idx % KXN;
  const float* Er = ws + OFF_ER + (size_t)n*HH*KXN*2;
  float sr = 0, si = 0;
  for (int h = 0; h < 128; ++h) {
    int t = (h*ky) & 127;
    float ar = Er[(h*KXN + kx)*2], ai = Er[(h*KXN + kx)*2 + 1];
    sr += ar*twr[t] - ai*twi[t];
    si += ar*twi[t] + ai*twr[t];
  }
  float sv = ws[OFF_SINV + (n*HH + ky)*KXN + kx];
  float* o = ws + OFF_EW + ((n*HH + ky)*KXN + kx)*2;
  o[0] = sr*sv; o[1] = si*sv;
}

__global__ __launch_bounds__(256) void k_ifft_cols(float* __restrict__ ws) {
  __shared__ float twr[128], twi[128];
  int tid = threadIdx.x;
  if (tid < 128) { float s, c; sincosf(-2.0f*PI_F*(float)tid/128.0f, &s, &c); twr[tid]=c; twi[tid]=s; }
  __syncthreads();
  int idx = blockIdx.x*256 + tid, n = blockIdx.y;
  if (idx >= HH*KXN) return;
  int h = idx / KXN, kx = idx % KXN;
  const float* EW = ws + OFF_EW + (size_t)n*HH*KXN*2;
  float sr = 0, si = 0;
  for (int ky = 0; ky < 128; ++ky) {
    int t = (h*ky) & 127;
    float ar = EW[(ky*KXN + kx)*2], ai = EW[(ky*KXN + kx)*2 + 1];
    sr += ar*twr[t] + ai*twi[t];
    si += ai*twr[t] - ar*twi[t];
  }
  float* o = ws + OFF_VR + ((n*HH + h)*KXN + kx)*2;
  o[0] = sr; o[1] = si;
}

__global__ __launch_bounds__(256) void k_ifft_rows(float* __restrict__ ws) {
  __shared__ float twr[128], twi[128];
  int tid = threadIdx.x;
  if (tid < 128) { float s, c; sincosf(-2.0f*PI_F*(float)tid/128.0f, &s, &c); twr[tid]=c; twi[tid]=s; }
  __syncthreads();
  int idx = blockIdx.x*256 + tid, n = blockIdx.y;
  int h = idx >> 7, w = idx & 127;
  const float* Vr = ws + OFF_VR + (size_t)n*HH*KXN*2;
  float s = 0.0f;
  for (int kx = 0; kx <= 64; ++kx) {
    int t = (w*kx) & 127;
    float ar = Vr[(h*KXN + kx)*2], ai = Vr[(h*KXN + kx)*2 + 1];
    float re = ar*twr[t] + ai*twi[t];
    s += (kx == 0 || kx == 64) ? re : 2.0f*re;
  }
  ws[OFF_WB + (n*HH + h)*WW + w] = s * (1.0f/16384.0f);
}

// ---------------------------------------------------------------------------
// x_new[n,c,p] = x[n,c,p] + sum_{a,b} psf[n,c,a,b]*wbuf[n,(ph-a+2)%128,(pw-b+2)%128]
// ---------------------------------------------------------------------------
__global__ __launch_bounds__(256) void k_xnew(const float* __restrict__ x,
                                              const float* __restrict__ dict,
                                              const float* __restrict__ ws,
                                              float* __restrict__ out) {
  __shared__ float psf_s[CIN*25];
  __shared__ float wt[20*20];
  int n = blockIdx.y, tile = blockIdx.x, tid = threadIdx.x;
  int h0 = (tile >> 3) * 16, w0 = (tile & 7) * 16;
  for (int i = tid; i < CIN*25; i += 256) psf_s[i] = dict[n*CIN*25 + i];
  for (int i = tid; i < 400; i += 256) {
    int r = i / 20, cc = i % 20;
    int gh = (h0 + r - 2) & 127, gw = (w0 + cc - 2) & 127;
    wt[i] = ws[OFF_WB + (n*HH + gh)*WW + gw];
  }
  __syncthreads();
  int py = tid >> 4, px = tid & 15;
  int h = h0+py, w = w0+px;
  for (int c = 0; c < CIN; ++c) {
    float acc = 0.0f;
    const float* pp = psf_s + c*25;
#pragma unroll
    for (int a = 0; a < 5; ++a)
#pragma unroll
      for (int b = 0; b < 5; ++b)
        acc += pp[a*5+b] * wt[(py + 4 - a)*20 + (px + 4 - b)];
    int gi = ((n*CIN + c)*HH + h)*WW + w;
    out[gi] = x[gi] + acc;
  }
}

// ---------------------------------------------------------------------------
// R[n,i,j,u,v] = sum_{h,w} xnew_i[h+u-4, w+v-4] * xnew_j[h,w]  (zero-pad)
// Conflict-free version: each lane owns a contiguous float4 of output pixels
// (w0 = 4*lane32), so ds_read_b128 windows are lane-consecutive 16B chunks
// (2-way bank aliasing = free). 3 aligned b128 per 12-dword window.
// ---------------------------------------------------------------------------
__global__ __launch_bounds__(256) void k_corr(const float* __restrict__ xn,
                                              float* __restrict__ ws) {
  __shared__ float xi_s[72*136];
  __shared__ float red_s[4][81];
  int n = blockIdx.y, p = blockIdx.x, tid = threadIdx.x;
  int ii = 0;
  while ((ii+1)*(ii+2)/2 <= p) ++ii;
  int jj = p - ii*(ii+1)/2;
  const float* Xi = xn + (size_t)(n*CIN + ii)*NPIX;
  const float* Xj = xn + (size_t)(n*CIN + jj)*NPIX;
  float acc[81];
#pragma unroll
  for (int t = 0; t < 81; ++t) acc[t] = 0.0f;

  int lane32 = tid & 31, rowg = tid >> 5;   // 8 rows per iteration
  int w0 = lane32 << 2;                     // contiguous float4 ownership

  for (int hh = 0; hh < 2; ++hh) {
    __syncthreads();
    for (int t = tid; t < 72*136; t += 256) {
      int r = t / 136, cc = t % 136;
      int gh = hh*64 - 4 + r, gw = cc - 4;
      float v = 0.0f;
      if (gh >= 0 && gh < 128 && gw >= 0 && gw < 128) v = Xi[gh*128 + gw];
      xi_s[t] = v;
    }
    __syncthreads();
    for (int it = 0; it < 8; ++it) {
      int hloc = it*8 + rowg;
      const float4 xjv = *reinterpret_cast<const float4*>(Xj + (hh*64 + hloc)*128 + w0);
      float xj0[4] = {xjv.x, xjv.y, xjv.z, xjv.w};
#pragma unroll
      for (int u = 0; u < 9; ++u) {
        const float* rp = &xi_s[(hloc + u)*136 + w0];
        const float4 a0 = *reinterpret_cast<const float4*>(rp + 0);
        const float4 a1 = *reinterpret_cast<const float4*>(rp + 4);
        const float4 a2 = *reinterpret_cast<const float4*>(rp + 8);
        float xw[12] = {a0.x,a0.y,a0.z,a0.w, a1.x,a1.y,a1.z,a1.w, a2.x,a2.y,a2.z,a2.w};
#pragma unroll
        for (int v = 0; v < 9; ++v)
#pragma unroll
          for (int kk = 0; kk < 4; ++kk)
            acc[u*9+v] += xw[v+kk] * xj0[kk];
      }
    }
  }
  int lane = tid & 63, wv = tid >> 6;
#pragma unroll
  for (int t = 0; t < 81; ++t) {
    float v = acc[t];
    v += __shfl_down(v, 32);
    v += __shfl_down(v, 16);
    v += __shfl_down(v, 8);
    v += __shfl_down(v, 4);
    v += __shfl_down(v, 2);
    v += __shfl_down(v, 1);
    if (lane == 0) red_s[wv][t] = v;
  }
  __syncthreads();
  if (tid < 81) {
    float s = red_s[0][tid] + red_s[1][tid] + red_s[2][tid] + red_s[3][tid];
    float* Rp = ws + OFF_R;
    Rp[((n*CIN + ii)*CIN + jj)*81 + tid] = s;
    Rp[((n*CIN + jj)*CIN + ii)*81 + (80 - tid)] = s;
  }
}

// ---------------------------------------------------------------------------
// Q[n,m1=(j,a,c), m2=(i,b,d)] = R[n,i,j,4+b-a,4+d-c] + (m1==m2)*a_d
// ---------------------------------------------------------------------------
__global__ __launch_bounds__(256) void k_build_q(const float* __restrict__ Rp,
                                                 const float* __restrict__ alpha_d,
                                                 const float* __restrict__ regp,
                                                 float* __restrict__ Q) {
  int idx = blockIdx.x*256 + threadIdx.x;      // < 10,240,000
  int m2 = idx % MMAT;
  int t  = idx / MMAT;
  int m1 = t % MMAT;
  int n  = t / MMAT;
  int i = m2 / 25, r2 = m2 % 25, b = r2 / 5, d = r2 % 5;
  int j = m1 / 25, r1 = m1 % 25, a = r1 / 5, c = r1 % 5;
  float v = Rp[((n*CIN + i)*CIN + j)*81 + (4 + b - a)*9 + (4 + d - c)];
  if (m1 == m2) v += alpha_d[n] * 16384.0f * regp[0] * (1.0f/1600.0f);
  Q[idx] = v;
}

// ---------------------------------------------------------------------------
// Pm[n, i*25+u*5+v] = sum_{h,w} xnew[n,i,h+u-2,w+v-2]*y[n,h,w] + a_d*d[n,0,i,u,v]
// ---------------------------------------------------------------------------
__global__ __launch_bounds__(256) void k_pm(const float* __restrict__ xn,
                                            const float* __restrict__ y,
                                            const float* __restrict__ dict,
                                            const float* __restrict__ alpha_d,
                                            const float* __restrict__ regp,
                                            float* __restrict__ ws) {
  __shared__ float xt[20*20];
  __shared__ float red_s[4][25];
  int n = blockIdx.y, i = blockIdx.x, tid = threadIdx.x;
  int py = tid >> 4, px = tid & 15;
  float acc[25];
#pragma unroll
  for (int t = 0; t < 25; ++t) acc[t] = 0.0f;
  const float* Xi = xn + (size_t)(n*CIN + i)*NPIX;
  for (int tile = 0; tile < 64; ++tile) {
    int h0 = (tile >> 3)*16, w0 = (tile & 7)*16;
    __syncthreads();
    for (int t = tid; t < 400; t += 256) {
      int r = t / 20, cc = t % 20;
      int gh = h0 + r - 2, gw = w0 + cc - 2;
      float v = 0.0f;
      if (gh >= 0 && gh < 128 && gw >= 0 && gw < 128) v = Xi[gh*128 + gw];
      xt[t] = v;
    }
    __syncthreads();
    float yv = y[(n*HH + h0 + py)*WW + w0 + px];
#pragma unroll
    for (int u = 0; u < 5; ++u)
#pragma unroll
      for (int v = 0; v < 5; ++v)
        acc[u*5+v] += xt[(py+u)*20 + (px+v)] * yv;
  }
  int lane = tid & 63, wv = tid >> 6;
#pragma unroll
  for (int t = 0; t < 25; ++t) {
    float v = acc[t];
    v += __shfl_down(v, 32);
    v += __shfl_down(v, 16);
    v += __shfl_down(v, 8);
    v += __shfl_down(v, 4);
    v += __shfl_down(v, 2);
    v += __shfl_down(v, 1);
    if (lane == 0) red_s[wv][t] = v;
  }
  __syncthreads();
  if (tid < 25) {
    float s = red_s[0][tid] + red_s[1][tid] + red_s[2][tid] + red_s[3][tid];
    float ad = alpha_d[n] * 16384.0f * regp[0] * (1.0f/1600.0f);
    ws[OFF_PM + n*MMAT + i*25 + tid] = s + ad * dict[(n*CIN + i)*25 + tid];
  }
}

// ---------------------------------------------------------------------------
// Fused Cholesky step: every block redundantly factorizes the 64x64 diag tile
// in LDS, then block b==0 writes it back while blocks b>=1 trsm their panel
// tile. Halves the launch count and uses 256 threads throughout.
// ---------------------------------------------------------------------------
__global__ __launch_bounds__(256) void k_chol_step(float* __restrict__ Q, int k) {
  __shared__ float Ld[64*65];
  __shared__ float V[64*65];
  int n = blockIdx.y, tid = threadIdx.x, b = blockIdx.x;
  float* Qn = Q + (size_t)n*MMAT*MMAT;
  int k0 = k*64;
  int r64 = tid & 63, g4 = tid >> 6;

  for (int idx = tid; idx < 4096; idx += 256) {
    int rr = idx >> 6, cc = idx & 63;
    Ld[rr*65+cc] = Qn[(size_t)(k0+rr)*MMAT + k0 + cc];
  }
  __syncthreads();

  // in-LDS right-looking Cholesky of the diag tile (redundant across blocks)
  for (int j = 0; j < 64; ++j) {
    if (tid == 0) Ld[j*65+j] = sqrtf(fmaxf(Ld[j*65+j], 1e-20f));
    __syncthreads();
    float inv = 1.0f / Ld[j*65+j];
    if (g4 == 0 && r64 > j) Ld[r64*65+j] *= inv;
    __syncthreads();
    if (r64 > j) {
      float lrj = Ld[r64*65+j];
      for (int c = j+1+g4; c <= r64; c += 4)
        Ld[r64*65+c] -= lrj * Ld[c*65+j];
    }
    __syncthreads();
  }

  if (b == 0) {
    for (int idx = tid; idx < 4096; idx += 256) {
      int rr = idx >> 6, cc = idx & 63;
      Qn[(size_t)(k0+rr)*MMAT + k0 + cc] = Ld[rr*65+cc];
    }
    return;
  }

  // panel trsm: V <- V * L^-T, rows independent; 4 lanes (a quad) per row
  int gr0 = k0 + 64*b;
  for (int idx = tid; idx < 4096; idx += 256) {
    int rr = idx >> 6, cc = idx & 63;
    V[rr*65+cc] = Qn[(size_t)(gr0+rr)*MMAT + k0 + cc];
  }
  __syncthreads();
  int wv = tid >> 6, lane = tid & 63;
  int pr = wv*16 + (lane >> 2);   // row handled by this quad
  int qg = lane & 3;              // position within quad
  for (int j = 0; j < 64; ++j) {
    float s = 0.0f;
    for (int t = qg; t < j; t += 4) s += V[pr*65+t] * Ld[j*65+t];
    s += __shfl_xor(s, 1);
    s += __shfl_xor(s, 2);
    if (qg == 0) V[pr*65+j] = (V[pr*65+j] - s) / Ld[j*65+j];
    __syncthreads();
  }
  for (int idx = tid; idx < 4096; idx += 256) {
    int rr = idx >> 6, cc = idx & 63;
    Qn[(size_t)(gr0+rr)*MMAT + k0 + cc] = V[rr*65+cc];
  }
}

__global__ __launch_bounds__(256) void k_chol_update(float* __restrict__ Q, int k) {
  __shared__ float As[64*68];
  __shared__ float Bs[64*68];
  int n = blockIdx.y, tid = threadIdx.x;
  float* Qn = Q + (size_t)n*MMAT*MMAT;
  int k0 = k*64, t0 = k0 + 64;
  int b = blockIdx.x;
  int ti = 0;
  while (((ti+1)*(ti+2))/2 <= b) ++ti;
  int tj = b - (ti*(ti+1))/2;
  int gr0 = t0 + ti*64, gc0 = t0 + tj*64;
  for (int idx = tid; idx < 4096; idx += 256) {
    int kk = idx & 63, r = idx >> 6;
    As[kk*68 + r] = Qn[(size_t)(gr0+r)*MMAT + k0 + kk];
    Bs[kk*68 + r] = Qn[(size_t)(gc0+r)*MMAT + k0 + kk];
  }
  __syncthreads();
  int tx = tid & 15, ty = tid >> 4;
  float accm[4][4];
#pragma unroll
  for (int r = 0; r < 4; ++r)
#pragma unroll
    for (int c = 0; c < 4; ++c) accm[r][c] = 0.0f;
  for (int kk = 0; kk < 64; ++kk) {
    const float4 av = *reinterpret_cast<const float4*>(&As[kk*68 + ty*4]);
    const float4 bv = *reinterpret_cast<const float4*>(&Bs[kk*68 + tx*4]);
    float ar[4] = {av.x, av.y, av.z, av.w};
    float br[4] = {bv.x, bv.y, bv.z, bv.w};
#pragma unroll
    for (int r = 0; r < 4; ++r)
#pragma unroll
      for (int c = 0; c < 4; ++c) accm[r][c] += ar[r]*br[c];
  }
#pragma unroll
  for (int r = 0; r < 4; ++r) {
    int gr = gr0 + ty*4 + r;
    float* qp = &Qn[(size_t)gr*MMAT + gc0 + tx*4];
    float4 cv = *reinterpret_cast<float4*>(qp);
    cv.x -= accm[r][0]; cv.y -= accm[r][1]; cv.z -= accm[r][2]; cv.w -= accm[r][3];
    *reinterpret_cast<float4*>(qp) = cv;
  }
}

// ---------------------------------------------------------------------------
// Blocked forward+backward triangular solve, 1024 threads per sample
// ---------------------------------------------------------------------------
__global__ __launch_bounds__(1024) void k_trsv(const float* __restrict__ Q,
                                               const float* __restrict__ Pm,
                                               float* __restrict__ out) {
  __shared__ float rhs[MMAT];
  __shared__ float Lk[64*68];
  int n = blockIdx.x, tid = threadIdx.x;
  const float* Qn = Q + (size_t)n*MMAT*MMAT;
  for (int i = tid; i < MMAT; i += 1024) rhs[i] = Pm[n*MMAT + i];
  __syncthreads();
  // forward: L z = p
  for (int kb = 0; kb < NBK; ++kb) {
    int g0 = kb*64;
    {
      int rr = tid >> 4, cc4 = (tid & 15) << 2;
      const float4 v = *reinterpret_cast<const float4*>(&Qn[(size_t)(g0+rr)*MMAT + g0 + cc4]);
      *reinterpret_cast<float4*>(&Lk[rr*68 + cc4]) = v;
    }
    __syncthreads();
    if (tid < 64) {
      float v = rhs[g0 + tid];
      for (int j = 0; j < 64; ++j) {
        if (tid == j) v = v / Lk[j*68+j];
        float zj = __shfl(v, j);
        if (tid > j) v -= Lk[tid*68+j]*zj;
      }
      rhs[g0+tid] = v;
    }
    __syncthreads();
    for (int i = g0 + 64 + tid; i < MMAT; i += 1024) {
      float v = rhs[i];
      const float4* r4 = reinterpret_cast<const float4*>(&Qn[(size_t)i*MMAT + g0]);
#pragma unroll
      for (int j4 = 0; j4 < 16; ++j4) {
        float4 q = r4[j4];
        v -= q.x*rhs[g0+4*j4] + q.y*rhs[g0+4*j4+1] + q.z*rhs[g0+4*j4+2] + q.w*rhs[g0+4*j4+3];
      }
      rhs[i] = v;
    }
    __syncthreads();
  }
  // backward: L^T x = z
  for (int kb = NBK-1; kb >= 0; --kb) {
    int g0 = kb*64;
    {
      int rr = tid >> 4, cc4 = (tid & 15) << 2;
      const float4 v = *reinterpret_cast<const float4*>(&Qn[(size_t)(g0+rr)*MMAT + g0 + cc4]);
      *reinterpret_cast<float4*>(&Lk[rr*68 + cc4]) = v;
    }
    __syncthreads();
    if (tid < 64) {
      float v = rhs[g0 + tid];
      for (int j = 63; j >= 0; --j) {
        if (tid == j) v = v / Lk[j*68+j];
        float xj = __shfl(v, j);
        if (tid < j) v -= Lk[j*68+tid]*xj;
      }
      rhs[g0+tid] = v;
    }
    __syncthreads();
    for (int i = tid; i < g0; i += 1024) {
      float s = 0.0f;
      for (int j = 0; j < 64; ++j)
        s += Qn[(size_t)(g0+j)*MMAT + i] * rhs[g0+j];
      rhs[i] -= s;
    }
    __syncthreads();
  }
  for (int i = tid; i < MMAT; i += 1024)
    out[4194304 + n*MMAT + i] = rhs[i];
}

// ---------------------------------------------------------------------------
extern "C" void kernel_launch(void* const* d_in, const int* in_sizes, int n_in,
                              void* d_out, int out_size, void* d_ws, size_t ws_size,
                              hipStream_t stream) {
  (void)in_sizes; (void)n_in; (void)out_size; (void)ws_size;
  const float* x    = (const float*)d_in[0];
  const float* dict = (const float*)d_in[1];
  const float* y    = (const float*)d_in[2];
  const float* ax   = (const float*)d_in[3];
  const float* ad   = (const float*)d_in[4];
  const float* regp = (const float*)d_in[5];
  float* out = (float*)d_out;
  float* ws  = (float*)d_ws;   // needs 47.75 MB

  dim3 b256(256);
  k_sinv<<<dim3(33,4), b256, 0, stream>>>(dict, ax, ws);
  k_e<<<dim3(64,4), b256, 0, stream>>>(x, dict, y, ws);
  k_fft_rows<<<dim3(33,4), b256, 0, stream>>>(ws);
  k_fft_cols<<<dim3(33,4), b256, 0, stream>>>(ws);
  k_ifft_cols<<<dim3(33,4), b256, 0, stream>>>(ws);
  k_ifft_rows<<<dim3(64,4), b256, 0, stream>>>(ws);
  k_xnew<<<dim3(64,4), b256, 0, stream>>>(x, dict, ws, out);
  k_corr<<<dim3(2080,4), b256, 0, stream>>>(out, ws);
  k_build_q<<<dim3(40000), b256, 0, stream>>>(ws + OFF_R, ad, regp, ws + OFF_Q);
  k_pm<<<dim3(64,4), b256, 0, stream>>>(out, y, dict, ad, regp, ws);

  float* Q = ws + OFF_Q;
  for (int k = 0; k < NBK; ++k) {
    int nt = NBK - 1 - k;
    k_chol_step<<<dim3(1 + nt, 4), b256, 0, stream>>>(Q, k);
    if (nt > 0)
      k_chol_update<<<dim3(nt*(nt+1)/2, 4), b256, 0, stream>>>(Q, k);
  }
  k_trsv<<<dim3(4), dim3(1024), 0, stream>>>(Q, ws + OFF_PM, out);
}

// Round 3
// 2095.036 us; speedup vs baseline: 2.6761x; 2.0312x over previous
//
#include <hip/hip_runtime.h>
#include <math.h>

#define PI_F 3.14159265358979323846f

#define NS   4
#define CIN  64
#define HH   128
#define WW   128
#define KXN  65          // rfft last-axis size
#define NPIX (HH*WW)
#define MMAT 1600        // CIN*5*5
#define NIT  20          // CG iterations

// float offsets in workspace
#define OFF_SINV 0
#define OFF_E    33280
#define OFF_ER   98816
#define OFF_EW   165376
#define OFF_VR   231936
#define OFF_WB   298496
#define OFF_R    364032
#define OFF_Q    1691136
#define OFF_PM   11931136
// CG state reuses the (dead-by-then) front-end scratch at offset 0:
#define OFF_DV   0          // 6400
#define OFF_RV   6400
#define OFF_PV   12800
#define OFF_AP   19200
#define OFF_SC   25600      // scalars: per-sample 64 slots (rr: 0..NIT, pAp: 32..32+NIT-1)

// ---------------------------------------------------------------------------
// Sinv[n,ky,kx] = 1 / (sum_c |D_c(ky,kx)|^2 + alpha_x/64); D from 5x5 psf DFT
// ---------------------------------------------------------------------------
__global__ __launch_bounds__(256) void k_sinv(const float* __restrict__ dict,
                                              const float* __restrict__ alpha_x,
                                              float* __restrict__ ws) {
  int idx = blockIdx.x * 256 + threadIdx.x;
  int n = blockIdx.y;
  if (idx >= HH * KXN) return;
  int ky = idx / KXN, kx = idx % KXN;
  float tr[25], ti[25];
  {
    float eyr[5], eyi[5], exr[5], exi[5];
#pragma unroll
    for (int a = 0; a < 5; ++a) {
      float s, c;
      sincosf(-2.0f * PI_F * (float)(ky * (a - 2)) / 128.0f, &s, &c);
      eyr[a] = c; eyi[a] = s;
      sincosf(-2.0f * PI_F * (float)(kx * (a - 2)) / 128.0f, &s, &c);
      exr[a] = c; exi[a] = s;
    }
#pragma unroll
    for (int a = 0; a < 5; ++a)
#pragma unroll
      for (int b = 0; b < 5; ++b) {
        tr[a*5+b] = eyr[a]*exr[b] - eyi[a]*exi[b];
        ti[a*5+b] = eyr[a]*exi[b] + eyi[a]*exr[b];
      }
  }
  const float* dn = dict + n * CIN * 25;
  float S = 0.0f;
  for (int c = 0; c < CIN; ++c) {
    const float* p = dn + c * 25;
    float Dr = 0.0f, Di = 0.0f;
#pragma unroll
    for (int t = 0; t < 25; ++t) { Dr += p[t]*tr[t]; Di += p[t]*ti[t]; }
    S += Dr*Dr + Di*Di;
  }
  float a = alpha_x[n] * (1.0f/64.0f);
  ws[OFF_SINV + (n*HH + ky)*KXN + kx] = 1.0f / (S + a);
}

// ---------------------------------------------------------------------------
// e[n,p] = y[n,p] - sum_c sum_{a,b} psf[n,c,a,b] * x[..circular..]
// ---------------------------------------------------------------------------
__global__ __launch_bounds__(256) void k_e(const float* __restrict__ x,
                                           const float* __restrict__ dict,
                                           const float* __restrict__ y,
                                           float* __restrict__ ws) {
  __shared__ float psf_s[CIN*25];
  __shared__ float xt[20*20];
  int n = blockIdx.y, tile = blockIdx.x, tid = threadIdx.x;
  int h0 = (tile >> 3) * 16, w0 = (tile & 7) * 16;
  for (int i = tid; i < CIN*25; i += 256) psf_s[i] = dict[n*CIN*25 + i];
  int py = tid >> 4, px = tid & 15;
  float acc = 0.0f;
  for (int c = 0; c < CIN; ++c) {
    __syncthreads();
    for (int i = tid; i < 400; i += 256) {
      int r = i / 20, cc = i % 20;
      int gh = (h0 + r - 2) & 127, gw = (w0 + cc - 2) & 127;
      xt[i] = x[((n*CIN + c)*HH + gh)*WW + gw];
    }
    __syncthreads();
    const float* pp = psf_s + c*25;
#pragma unroll
    for (int a = 0; a < 5; ++a)
#pragma unroll
      for (int b = 0; b < 5; ++b)
        acc += pp[a*5+b] * xt[(py+a)*20 + (px+b)];
  }
  int h = h0+py, w = w0+px;
  ws[OFF_E + (n*HH + h)*WW + w] = y[(n*HH + h)*WW + w] - acc;
}

// ---------------------------------------------------------------------------
// tiny table-DFT kernels (only 4 images each way)
// ---------------------------------------------------------------------------
__global__ __launch_bounds__(256) void k_fft_rows(float* __restrict__ ws) {
  __shared__ float twr[128], twi[128];
  int tid = threadIdx.x;
  if (tid < 128) { float s, c; sincosf(-2.0f*PI_F*(float)tid/128.0f, &s, &c); twr[tid]=c; twi[tid]=s; }
  __syncthreads();
  int idx = blockIdx.x*256 + tid, n = blockIdx.y;
  if (idx >= HH*KXN) return;
  int h = idx / KXN, k = idx % KXN;
  const float* row = ws + OFF_E + (n*HH + h)*WW;
  float sr = 0, si = 0;
  for (int w = 0; w < 128; ++w) {
    int t = (w*k) & 127;
    float v = row[w];
    sr += v*twr[t]; si += v*twi[t];
  }
  float* o = ws + OFF_ER + ((n*HH + h)*KXN + k)*2;
  o[0] = sr; o[1] = si;
}

__global__ __launch_bounds__(256) void k_fft_cols(float* __restrict__ ws) {
  __shared__ float twr[128], twi[128];
  int tid = threadIdx.x;
  if (tid < 128) { float s, c; sincosf(-2.0f*PI_F*(float)tid/128.0f, &s, &c); twr[tid]=c; twi[tid]=s; }
  __syncthreads();
  int idx = blockIdx.x*256 + tid, n = blockIdx.y;
  if (idx >= HH*KXN) return;
  int ky = idx / KXN, kx = idx % KXN;
  const float* Er = ws + OFF_ER + (size_t)n*HH*KXN*2;
  float sr = 0, si = 0;
  for (int h = 0; h < 128; ++h) {
    int t = (h*ky) & 127;
    float ar = Er[(h*KXN + kx)*2], ai = Er[(h*KXN + kx)*2 + 1];
    sr += ar*twr[t] - ai*twi[t];
    si += ar*twi[t] + ai*twr[t];
  }
  float sv = ws[OFF_SINV + (n*HH + ky)*KXN + kx];
  float* o = ws + OFF_EW + ((n*HH + ky)*KXN + kx)*2;
  o[0] = sr*sv; o[1] = si*sv;
}

__global__ __launch_bounds__(256) void k_ifft_cols(float* __restrict__ ws) {
  __shared__ float twr[128], twi[128];
  int tid = threadIdx.x;
  if (tid < 128) { float s, c; sincosf(-2.0f*PI_F*(float)tid/128.0f, &s, &c); twr[tid]=c; twi[tid]=s; }
  __syncthreads();
  int idx = blockIdx.x*256 + tid, n = blockIdx.y;
  if (idx >= HH*KXN) return;
  int h = idx / KXN, kx = idx % KXN;
  const float* EW = ws + OFF_EW + (size_t)n*HH*KXN*2;
  float sr = 0, si = 0;
  for (int ky = 0; ky < 128; ++ky) {
    int t = (h*ky) & 127;
    float ar = EW[(ky*KXN + kx)*2], ai = EW[(ky*KXN + kx)*2 + 1];
    sr += ar*twr[t] + ai*twi[t];
    si += ai*twr[t] - ar*twi[t];
  }
  float* o = ws + OFF_VR + ((n*HH + h)*KXN + kx)*2;
  o[0] = sr; o[1] = si;
}

__global__ __launch_bounds__(256) void k_ifft_rows(float* __restrict__ ws) {
  __shared__ float twr[128], twi[128];
  int tid = threadIdx.x;
  if (tid < 128) { float s, c; sincosf(-2.0f*PI_F*(float)tid/128.0f, &s, &c); twr[tid]=c; twi[tid]=s; }
  __syncthreads();
  int idx = blockIdx.x*256 + tid, n = blockIdx.y;
  int h = idx >> 7, w = idx & 127;
  const float* Vr = ws + OFF_VR + (size_t)n*HH*KXN*2;
  float s = 0.0f;
  for (int kx = 0; kx <= 64; ++kx) {
    int t = (w*kx) & 127;
    float ar = Vr[(h*KXN + kx)*2], ai = Vr[(h*KXN + kx)*2 + 1];
    float re = ar*twr[t] + ai*twi[t];
    s += (kx == 0 || kx == 64) ? re : 2.0f*re;
  }
  ws[OFF_WB + (n*HH + h)*WW + w] = s * (1.0f/16384.0f);
}

// ---------------------------------------------------------------------------
// x_new[n,c,p] = x[n,c,p] + sum_{a,b} psf[n,c,a,b]*wbuf[circ]
// ---------------------------------------------------------------------------
__global__ __launch_bounds__(256) void k_xnew(const float* __restrict__ x,
                                              const float* __restrict__ dict,
                                              const float* __restrict__ ws,
                                              float* __restrict__ out) {
  __shared__ float psf_s[CIN*25];
  __shared__ float wt[20*20];
  int n = blockIdx.y, tile = blockIdx.x, tid = threadIdx.x;
  int h0 = (tile >> 3) * 16, w0 = (tile & 7) * 16;
  for (int i = tid; i < CIN*25; i += 256) psf_s[i] = dict[n*CIN*25 + i];
  for (int i = tid; i < 400; i += 256) {
    int r = i / 20, cc = i % 20;
    int gh = (h0 + r - 2) & 127, gw = (w0 + cc - 2) & 127;
    wt[i] = ws[OFF_WB + (n*HH + gh)*WW + gw];
  }
  __syncthreads();
  int py = tid >> 4, px = tid & 15;
  int h = h0+py, w = w0+px;
  for (int c = 0; c < CIN; ++c) {
    float acc = 0.0f;
    const float* pp = psf_s + c*25;
#pragma unroll
    for (int a = 0; a < 5; ++a)
#pragma unroll
      for (int b = 0; b < 5; ++b)
        acc += pp[a*5+b] * wt[(py + 4 - a)*20 + (px + 4 - b)];
    int gi = ((n*CIN + c)*HH + h)*WW + w;
    out[gi] = x[gi] + acc;
  }
}

// ---------------------------------------------------------------------------
// R[n,i,j,u,v] = sum_{h,w} xnew_i[h+u-4, w+v-4] * xnew_j[h,w]  (zero-pad)
// Register-blocked sliding window: each thread owns 8 consecutive Xj rows
// (float4 of columns, in registers) and slides through 16 xi_s rows; each
// 12-dword LDS window feeds up to 9*4-wide FMA groups -> 4.5x fewer LDS reads
// than the per-u version (which was LDS-throughput-bound).
// ---------------------------------------------------------------------------
__global__ __launch_bounds__(256) void k_corr(const float* __restrict__ xn,
                                              float* __restrict__ ws) {
  __shared__ float xi_s[72*136];
  __shared__ float red_s[4][81];
  int n = blockIdx.y, p = blockIdx.x, tid = threadIdx.x;
  int ii = 0;
  while ((ii+1)*(ii+2)/2 <= p) ++ii;
  int jj = p - ii*(ii+1)/2;
  const float* Xi = xn + (size_t)(n*CIN + ii)*NPIX;
  const float* Xj = xn + (size_t)(n*CIN + jj)*NPIX;
  float acc[81];
#pragma unroll
  for (int t = 0; t < 81; ++t) acc[t] = 0.0f;

  int lane32 = tid & 31, rowg = tid >> 5;   // 8 row-groups of 8 rows
  int w0 = lane32 << 2;                     // contiguous float4 column ownership

  for (int hh = 0; hh < 2; ++hh) {
    __syncthreads();
    for (int t = tid; t < 72*136; t += 256) {
      int r = t / 136, cc = t % 136;
      int gh = hh*64 - 4 + r, gw = cc - 4;
      float v = 0.0f;
      if (gh >= 0 && gh < 128 && gw >= 0 && gw < 128) v = Xi[gh*128 + gw];
      xi_s[t] = v;
    }
    __syncthreads();
    // own 8 Xj rows in registers
    float xj[8][4];
#pragma unroll
    for (int r = 0; r < 8; ++r) {
      const float4 v = *reinterpret_cast<const float4*>(Xj + (hh*64 + rowg*8 + r)*128 + w0);
      xj[r][0]=v.x; xj[r][1]=v.y; xj[r][2]=v.z; xj[r][3]=v.w;
    }
#pragma unroll
    for (int t = 0; t < 16; ++t) {
      const float* rp = &xi_s[(rowg*8 + t)*136 + w0];
      const float4 a0 = *reinterpret_cast<const float4*>(rp + 0);
      const float4 a1 = *reinterpret_cast<const float4*>(rp + 4);
      const float4 a2 = *reinterpret_cast<const float4*>(rp + 8);
      float xw[12] = {a0.x,a0.y,a0.z,a0.w, a1.x,a1.y,a1.z,a1.w, a2.x,a2.y,a2.z,a2.w};
#pragma unroll
      for (int u = 0; u < 9; ++u) {
        const int jr = t - u;              // local Xj row index
        if (jr >= 0 && jr < 8) {
#pragma unroll
          for (int v = 0; v < 9; ++v)
#pragma unroll
            for (int kk = 0; kk < 4; ++kk)
              acc[u*9+v] += xw[v+kk] * xj[jr][kk];
        }
      }
    }
  }
  int lane = tid & 63, wv = tid >> 6;
#pragma unroll
  for (int t = 0; t < 81; ++t) {
    float v = acc[t];
    v += __shfl_down(v, 32);
    v += __shfl_down(v, 16);
    v += __shfl_down(v, 8);
    v += __shfl_down(v, 4);
    v += __shfl_down(v, 2);
    v += __shfl_down(v, 1);
    if (lane == 0) red_s[wv][t] = v;
  }
  __syncthreads();
  if (tid < 81) {
    float s = red_s[0][tid] + red_s[1][tid] + red_s[2][tid] + red_s[3][tid];
    float* Rp = ws + OFF_R;
    Rp[((n*CIN + ii)*CIN + jj)*81 + tid] = s;
    Rp[((n*CIN + jj)*CIN + ii)*81 + (80 - tid)] = s;
  }
}

// ---------------------------------------------------------------------------
// Q[n,m1=(j,a,c), m2=(i,b,d)] = R[n,i,j,4+b-a,4+d-c] + (m1==m2)*a_d
// ---------------------------------------------------------------------------
__global__ __launch_bounds__(256) void k_build_q(const float* __restrict__ Rp,
                                                 const float* __restrict__ alpha_d,
                                                 const float* __restrict__ regp,
                                                 float* __restrict__ Q) {
  int idx = blockIdx.x*256 + threadIdx.x;      // < 10,240,000
  int m2 = idx % MMAT;
  int t  = idx / MMAT;
  int m1 = t % MMAT;
  int n  = t / MMAT;
  int i = m2 / 25, r2 = m2 % 25, b = r2 / 5, d = r2 % 5;
  int j = m1 / 25, r1 = m1 % 25, a = r1 / 5, c = r1 % 5;
  float v = Rp[((n*CIN + i)*CIN + j)*81 + (4 + b - a)*9 + (4 + d - c)];
  if (m1 == m2) v += alpha_d[n] * 16384.0f * regp[0] * (1.0f/1600.0f);
  Q[idx] = v;
}

// ---------------------------------------------------------------------------
// Pm[n, i*25+u*5+v] = sum_{h,w} xnew[n,i,h+u-2,w+v-2]*y[n,h,w] + a_d*d[...]
// ---------------------------------------------------------------------------
__global__ __launch_bounds__(256) void k_pm(const float* __restrict__ xn,
                                            const float* __restrict__ y,
                                            const float* __restrict__ dict,
                                            const float* __restrict__ alpha_d,
                                            const float* __restrict__ regp,
                                            float* __restrict__ ws) {
  __shared__ float xt[20*20];
  __shared__ float red_s[4][25];
  int n = blockIdx.y, i = blockIdx.x, tid = threadIdx.x;
  int py = tid >> 4, px = tid & 15;
  float acc[25];
#pragma unroll
  for (int t = 0; t < 25; ++t) acc[t] = 0.0f;
  const float* Xi = xn + (size_t)(n*CIN + i)*NPIX;
  for (int tile = 0; tile < 64; ++tile) {
    int h0 = (tile >> 3)*16, w0 = (tile & 7)*16;
    __syncthreads();
    for (int t = tid; t < 400; t += 256) {
      int r = t / 20, cc = t % 20;
      int gh = h0 + r - 2, gw = w0 + cc - 2;
      float v = 0.0f;
      if (gh >= 0 && gh < 128 && gw >= 0 && gw < 128) v = Xi[gh*128 + gw];
      xt[t] = v;
    }
    __syncthreads();
    float yv = y[(n*HH + h0 + py)*WW + w0 + px];
#pragma unroll
    for (int u = 0; u < 5; ++u)
#pragma unroll
      for (int v = 0; v < 5; ++v)
        acc[u*5+v] += xt[(py+u)*20 + (px+v)] * yv;
  }
  int lane = tid & 63, wv = tid >> 6;
#pragma unroll
  for (int t = 0; t < 25; ++t) {
    float v = acc[t];
    v += __shfl_down(v, 32);
    v += __shfl_down(v, 16);
    v += __shfl_down(v, 8);
    v += __shfl_down(v, 4);
    v += __shfl_down(v, 2);
    v += __shfl_down(v, 1);
    if (lane == 0) red_s[wv][t] = v;
  }
  __syncthreads();
  if (tid < 25) {
    float s = red_s[0][tid] + red_s[1][tid] + red_s[2][tid] + red_s[3][tid];
    float ad = alpha_d[n] * 16384.0f * regp[0] * (1.0f/1600.0f);
    ws[OFF_PM + n*MMAT + i*25 + tid] = s + ad * dict[(n*CIN + i)*25 + tid];
  }
}

// ---------------------------------------------------------------------------
// CG solver for Q d = Pm  (Q SPD, kappa ~ 4 by Marchenko-Pastur; 20 iters)
// ---------------------------------------------------------------------------
__global__ __launch_bounds__(256) void k_cg_zero(float* __restrict__ ws) {
  ws[OFF_SC + threadIdx.x] = 0.0f;   // 256 scalar slots
}

__global__ __launch_bounds__(256) void k_cg_init(float* __restrict__ ws) {
  int n = blockIdx.y, i = blockIdx.x*256 + threadIdx.x;
  float pval = 0.0f;
  if (i < MMAT) {
    pval = ws[OFF_PM + n*MMAT + i];
    ws[OFF_DV + n*MMAT + i] = 0.0f;
    ws[OFF_RV + n*MMAT + i] = pval;
    ws[OFF_PV + n*MMAT + i] = pval;
  }
  float part = pval*pval;
  part += __shfl_down(part, 32);
  part += __shfl_down(part, 16);
  part += __shfl_down(part, 8);
  part += __shfl_down(part, 4);
  part += __shfl_down(part, 2);
  part += __shfl_down(part, 1);
  __shared__ float red[4];
  int lane = threadIdx.x & 63, wv = threadIdx.x >> 6;
  if (lane == 0) red[wv] = part;
  __syncthreads();
  if (threadIdx.x == 0)
    atomicAdd(&ws[OFF_SC + n*64 + 0], red[0]+red[1]+red[2]+red[3]);
}

// Ap = Q p ; accumulate pAp. 1 wave per row; grid (MMAT/4, NS)
__global__ __launch_bounds__(256) void k_cg_matvec(const float* __restrict__ Q,
                                                   float* __restrict__ ws, int it) {
  int n = blockIdx.y, tid = threadIdx.x;
  int wv = tid >> 6, lane = tid & 63;
  int row = blockIdx.x*4 + wv;
  const float* Qrow = Q + ((size_t)n*MMAT + row)*MMAT;
  const float* pv = ws + OFF_PV + n*MMAT;
  float acc = 0.0f;
#pragma unroll
  for (int t = 0; t < 25; ++t)
    acc += Qrow[lane + 64*t] * pv[lane + 64*t];
  acc += __shfl_down(acc, 32);
  acc += __shfl_down(acc, 16);
  acc += __shfl_down(acc, 8);
  acc += __shfl_down(acc, 4);
  acc += __shfl_down(acc, 2);
  acc += __shfl_down(acc, 1);
  __shared__ float red[4];
  if (lane == 0) {
    ws[OFF_AP + n*MMAT + row] = acc;
    red[wv] = acc * pv[row];
  }
  __syncthreads();
  if (tid == 0)
    atomicAdd(&ws[OFF_SC + n*64 + 32 + it], red[0]+red[1]+red[2]+red[3]);
}

// d += alpha p; r -= alpha Ap; rr_{it+1} = r.r ; optionally write d to out
__global__ __launch_bounds__(256) void k_cg_update(float* __restrict__ ws, int it,
                                                   int last, float* __restrict__ out) {
  int n = blockIdx.y, i = blockIdx.x*256 + threadIdx.x;
  float rr  = ws[OFF_SC + n*64 + it];
  float pap = ws[OFF_SC + n*64 + 32 + it];
  float alpha = rr / (pap + 1e-30f);
  float rn = 0.0f;
  if (i < MMAT) {
    float dv = ws[OFF_DV + n*MMAT + i] + alpha * ws[OFF_PV + n*MMAT + i];
    rn = ws[OFF_RV + n*MMAT + i] - alpha * ws[OFF_AP + n*MMAT + i];
    ws[OFF_DV + n*MMAT + i] = dv;
    ws[OFF_RV + n*MMAT + i] = rn;
    if (last) out[4194304 + n*MMAT + i] = dv;
  }
  float part = rn*rn;
  part += __shfl_down(part, 32);
  part += __shfl_down(part, 16);
  part += __shfl_down(part, 8);
  part += __shfl_down(part, 4);
  part += __shfl_down(part, 2);
  part += __shfl_down(part, 1);
  __shared__ float red[4];
  int lane = threadIdx.x & 63, wv = threadIdx.x >> 6;
  if (lane == 0) red[wv] = part;
  __syncthreads();
  if (threadIdx.x == 0)
    atomicAdd(&ws[OFF_SC + n*64 + it + 1], red[0]+red[1]+red[2]+red[3]);
}

// p = r + beta p
__global__ __launch_bounds__(256) void k_cg_pupd(float* __restrict__ ws, int it) {
  int n = blockIdx.y, i = blockIdx.x*256 + threadIdx.x;
  if (i >= MMAT) return;
  float beta = ws[OFF_SC + n*64 + it + 1] / (ws[OFF_SC + n*64 + it] + 1e-30f);
  ws[OFF_PV + n*MMAT + i] = ws[OFF_RV + n*MMAT + i] + beta * ws[OFF_PV + n*MMAT + i];
}

// ---------------------------------------------------------------------------
extern "C" void kernel_launch(void* const* d_in, const int* in_sizes, int n_in,
                              void* d_out, int out_size, void* d_ws, size_t ws_size,
                              hipStream_t stream) {
  (void)in_sizes; (void)n_in; (void)out_size; (void)ws_size;
  const float* x    = (const float*)d_in[0];
  const float* dict = (const float*)d_in[1];
  const float* y    = (const float*)d_in[2];
  const float* ax   = (const float*)d_in[3];
  const float* ad   = (const float*)d_in[4];
  const float* regp = (const float*)d_in[5];
  float* out = (float*)d_out;
  float* ws  = (float*)d_ws;   // needs 47.75 MB

  dim3 b256(256);
  k_sinv<<<dim3(33,4), b256, 0, stream>>>(dict, ax, ws);
  k_e<<<dim3(64,4), b256, 0, stream>>>(x, dict, y, ws);
  k_fft_rows<<<dim3(33,4), b256, 0, stream>>>(ws);
  k_fft_cols<<<dim3(33,4), b256, 0, stream>>>(ws);
  k_ifft_cols<<<dim3(33,4), b256, 0, stream>>>(ws);
  k_ifft_rows<<<dim3(64,4), b256, 0, stream>>>(ws);
  k_xnew<<<dim3(64,4), b256, 0, stream>>>(x, dict, ws, out);
  k_corr<<<dim3(2080,4), b256, 0, stream>>>(out, ws);
  k_build_q<<<dim3(40000), b256, 0, stream>>>(ws + OFF_R, ad, regp, ws + OFF_Q);
  k_pm<<<dim3(64,4), b256, 0, stream>>>(out, y, dict, ad, regp, ws);

  // ---- CG solve (replaces Cholesky + trsv) ----
  float* Q = ws + OFF_Q;
  k_cg_zero<<<dim3(1), b256, 0, stream>>>(ws);
  k_cg_init<<<dim3(7,4), b256, 0, stream>>>(ws);
  for (int it = 0; it < NIT; ++it) {
    k_cg_matvec<<<dim3(MMAT/4, 4), b256, 0, stream>>>(Q, ws, it);
    k_cg_update<<<dim3(7,4), b256, 0, stream>>>(ws, it, (it == NIT-1) ? 1 : 0, out);
    if (it < NIT-1)
      k_cg_pupd<<<dim3(7,4), b256, 0, stream>>>(ws, it);
  }
}

// Round 4
// 1227.960 us; speedup vs baseline: 4.5657x; 1.7061x over previous
//
#include <hip/hip_runtime.h>
#include <math.h>

#define PI_F 3.14159265358979323846f

#define NS   4
#define CIN  64
#define HH   128
#define WW   128
#define KXN  65          // rfft last-axis size
#define NPIX (HH*WW)
#define MMAT 1600        // CIN*5*5
#define NIT  14          // CG iterations

// float offsets in workspace (total ~6.8 MB now; Q no longer materialized)
#define OFF_SINV 0
#define OFF_E    33280
#define OFF_ER   98816
#define OFF_EW   165376
#define OFF_VR   231936
#define OFF_WB   298496
#define OFF_R    364032      // 4*64*64*81 = 1,327,104 floats
#define OFF_PM   1691136    // 6400 floats
// CG state reuses the (dead-by-then) front-end scratch at offset 0:
#define OFF_DV   0
#define OFF_RV   6400
#define OFF_PV   12800
#define OFF_AP   19200
#define OFF_SC   25600      // per-sample 64 slots: rr at [it], pAp at [32+it]

#define WRED(x) { (x)+=__shfl_down((x),32); (x)+=__shfl_down((x),16); (x)+=__shfl_down((x),8); \
                  (x)+=__shfl_down((x),4);  (x)+=__shfl_down((x),2);  (x)+=__shfl_down((x),1); }

// ---------------------------------------------------------------------------
// Sinv[n,ky,kx] = 1 / (sum_c |D_c(ky,kx)|^2 + alpha_x/64); D from 5x5 psf DFT
// ---------------------------------------------------------------------------
__global__ __launch_bounds__(256) void k_sinv(const float* __restrict__ dict,
                                              const float* __restrict__ alpha_x,
                                              float* __restrict__ ws) {
  int idx = blockIdx.x * 256 + threadIdx.x;
  int n = blockIdx.y;
  if (idx >= HH * KXN) return;
  int ky = idx / KXN, kx = idx % KXN;
  float tr[25], ti[25];
  {
    float eyr[5], eyi[5], exr[5], exi[5];
#pragma unroll
    for (int a = 0; a < 5; ++a) {
      float s, c;
      sincosf(-2.0f * PI_F * (float)(ky * (a - 2)) / 128.0f, &s, &c);
      eyr[a] = c; eyi[a] = s;
      sincosf(-2.0f * PI_F * (float)(kx * (a - 2)) / 128.0f, &s, &c);
      exr[a] = c; exi[a] = s;
    }
#pragma unroll
    for (int a = 0; a < 5; ++a)
#pragma unroll
      for (int b = 0; b < 5; ++b) {
        tr[a*5+b] = eyr[a]*exr[b] - eyi[a]*exi[b];
        ti[a*5+b] = eyr[a]*exi[b] + eyi[a]*exr[b];
      }
  }
  const float* dn = dict + n * CIN * 25;
  float S = 0.0f;
  for (int c = 0; c < CIN; ++c) {
    const float* p = dn + c * 25;
    float Dr = 0.0f, Di = 0.0f;
#pragma unroll
    for (int t = 0; t < 25; ++t) { Dr += p[t]*tr[t]; Di += p[t]*ti[t]; }
    S += Dr*Dr + Di*Di;
  }
  float a = alpha_x[n] * (1.0f/64.0f);
  ws[OFF_SINV + (n*HH + ky)*KXN + kx] = 1.0f / (S + a);
}

// ---------------------------------------------------------------------------
// e[n,p] = y[n,p] - sum_c sum_{a,b} psf[n,c,a,b] * x[..circular..]
// ---------------------------------------------------------------------------
__global__ __launch_bounds__(256) void k_e(const float* __restrict__ x,
                                           const float* __restrict__ dict,
                                           const float* __restrict__ y,
                                           float* __restrict__ ws) {
  __shared__ float psf_s[CIN*25];
  __shared__ float xt[20*20];
  int n = blockIdx.y, tile = blockIdx.x, tid = threadIdx.x;
  int h0 = (tile >> 3) * 16, w0 = (tile & 7) * 16;
  for (int i = tid; i < CIN*25; i += 256) psf_s[i] = dict[n*CIN*25 + i];
  int py = tid >> 4, px = tid & 15;
  float acc = 0.0f;
  for (int c = 0; c < CIN; ++c) {
    __syncthreads();
    for (int i = tid; i < 400; i += 256) {
      int r = i / 20, cc = i % 20;
      int gh = (h0 + r - 2) & 127, gw = (w0 + cc - 2) & 127;
      xt[i] = x[((n*CIN + c)*HH + gh)*WW + gw];
    }
    __syncthreads();
    const float* pp = psf_s + c*25;
#pragma unroll
    for (int a = 0; a < 5; ++a)
#pragma unroll
      for (int b = 0; b < 5; ++b)
        acc += pp[a*5+b] * xt[(py+a)*20 + (px+b)];
  }
  int h = h0+py, w = w0+px;
  ws[OFF_E + (n*HH + h)*WW + w] = y[(n*HH + h)*WW + w] - acc;
}

// ---------------------------------------------------------------------------
// tiny table-DFT kernels (only 4 images each way)
// ---------------------------------------------------------------------------
__global__ __launch_bounds__(256) void k_fft_rows(float* __restrict__ ws) {
  __shared__ float twr[128], twi[128];
  int tid = threadIdx.x;
  if (tid < 128) { float s, c; sincosf(-2.0f*PI_F*(float)tid/128.0f, &s, &c); twr[tid]=c; twi[tid]=s; }
  __syncthreads();
  int idx = blockIdx.x*256 + tid, n = blockIdx.y;
  if (idx >= HH*KXN) return;
  int h = idx / KXN, k = idx % KXN;
  const float* row = ws + OFF_E + (n*HH + h)*WW;
  float sr = 0, si = 0;
  for (int w = 0; w < 128; ++w) {
    int t = (w*k) & 127;
    float v = row[w];
    sr += v*twr[t]; si += v*twi[t];
  }
  float* o = ws + OFF_ER + ((n*HH + h)*KXN + k)*2;
  o[0] = sr; o[1] = si;
}

__global__ __launch_bounds__(256) void k_fft_cols(float* __restrict__ ws) {
  __shared__ float twr[128], twi[128];
  int tid = threadIdx.x;
  if (tid < 128) { float s, c; sincosf(-2.0f*PI_F*(float)tid/128.0f, &s, &c); twr[tid]=c; twi[tid]=s; }
  __syncthreads();
  int idx = blockIdx.x*256 + tid, n = blockIdx.y;
  if (idx >= HH*KXN) return;
  int ky = idx / KXN, kx = idx % KXN;
  const float* Er = ws + OFF_ER + (size_t)n*HH*KXN*2;
  float sr = 0, si = 0;
  for (int h = 0; h < 128; ++h) {
    int t = (h*ky) & 127;
    float ar = Er[(h*KXN + kx)*2], ai = Er[(h*KXN + kx)*2 + 1];
    sr += ar*twr[t] - ai*twi[t];
    si += ar*twi[t] + ai*twr[t];
  }
  float sv = ws[OFF_SINV + (n*HH + ky)*KXN + kx];
  float* o = ws + OFF_EW + ((n*HH + ky)*KXN + kx)*2;
  o[0] = sr*sv; o[1] = si*sv;
}

__global__ __launch_bounds__(256) void k_ifft_cols(float* __restrict__ ws) {
  __shared__ float twr[128], twi[128];
  int tid = threadIdx.x;
  if (tid < 128) { float s, c; sincosf(-2.0f*PI_F*(float)tid/128.0f, &s, &c); twr[tid]=c; twi[tid]=s; }
  __syncthreads();
  int idx = blockIdx.x*256 + tid, n = blockIdx.y;
  if (idx >= HH*KXN) return;
  int h = idx / KXN, kx = idx % KXN;
  const float* EW = ws + OFF_EW + (size_t)n*HH*KXN*2;
  float sr = 0, si = 0;
  for (int ky = 0; ky < 128; ++ky) {
    int t = (h*ky) & 127;
    float ar = EW[(ky*KXN + kx)*2], ai = EW[(ky*KXN + kx)*2 + 1];
    sr += ar*twr[t] + ai*twi[t];
    si += ai*twr[t] - ar*twi[t];
  }
  float* o = ws + OFF_VR + ((n*HH + h)*KXN + kx)*2;
  o[0] = sr; o[1] = si;
}

__global__ __launch_bounds__(256) void k_ifft_rows(float* __restrict__ ws) {
  __shared__ float twr[128], twi[128];
  int tid = threadIdx.x;
  if (tid < 128) { float s, c; sincosf(-2.0f*PI_F*(float)tid/128.0f, &s, &c); twr[tid]=c; twi[tid]=s; }
  __syncthreads();
  int idx = blockIdx.x*256 + tid, n = blockIdx.y;
  int h = idx >> 7, w = idx & 127;
  const float* Vr = ws + OFF_VR + (size_t)n*HH*KXN*2;
  float s = 0.0f;
  for (int kx = 0; kx <= 64; ++kx) {
    int t = (w*kx) & 127;
    float ar = Vr[(h*KXN + kx)*2], ai = Vr[(h*KXN + kx)*2 + 1];
    float re = ar*twr[t] + ai*twi[t];
    s += (kx == 0 || kx == 64) ? re : 2.0f*re;
  }
  ws[OFF_WB + (n*HH + h)*WW + w] = s * (1.0f/16384.0f);
}

// ---------------------------------------------------------------------------
// x_new[n,c,p] = x[n,c,p] + sum_{a,b} psf[n,c,a,b]*wbuf[circ]
// ---------------------------------------------------------------------------
__global__ __launch_bounds__(256) void k_xnew(const float* __restrict__ x,
                                              const float* __restrict__ dict,
                                              const float* __restrict__ ws,
                                              float* __restrict__ out) {
  __shared__ float psf_s[CIN*25];
  __shared__ float wt[20*20];
  int n = blockIdx.y, tile = blockIdx.x, tid = threadIdx.x;
  int h0 = (tile >> 3) * 16, w0 = (tile & 7) * 16;
  for (int i = tid; i < CIN*25; i += 256) psf_s[i] = dict[n*CIN*25 + i];
  for (int i = tid; i < 400; i += 256) {
    int r = i / 20, cc = i % 20;
    int gh = (h0 + r - 2) & 127, gw = (w0 + cc - 2) & 127;
    wt[i] = ws[OFF_WB + (n*HH + gh)*WW + gw];
  }
  __syncthreads();
  int py = tid >> 4, px = tid & 15;
  int h = h0+py, w = w0+px;
  for (int c = 0; c < CIN; ++c) {
    float acc = 0.0f;
    const float* pp = psf_s + c*25;
#pragma unroll
    for (int a = 0; a < 5; ++a)
#pragma unroll
      for (int b = 0; b < 5; ++b)
        acc += pp[a*5+b] * wt[(py + 4 - a)*20 + (px + 4 - b)];
    int gi = ((n*CIN + c)*HH + h)*WW + w;
    out[gi] = x[gi] + acc;
  }
}

// ---------------------------------------------------------------------------
// R[n,i,j,u,v] = sum_{h,w} xnew_i[h+u-4, w+v-4] * xnew_j[h,w]  (zero-pad)
// u-split across waves (acc<=27 per thread -> stays in VGPRs, no AGPR moves);
// quarter-row staging (40x136 = 21.8 KB LDS -> 7 blocks/CU).
// wave w owns u in {w, w+4} (+ u=8 on wave 3); per-wave reduce + direct write.
// ---------------------------------------------------------------------------
__global__ __launch_bounds__(256, 6) void k_corr(const float* __restrict__ xn,
                                                 float* __restrict__ ws) {
  __shared__ float xi_s[40*136];
  int n = blockIdx.y, p = blockIdx.x, tid = threadIdx.x;
  int ii = 0;
  while ((ii+1)*(ii+2)/2 <= p) ++ii;
  int jj = p - ii*(ii+1)/2;
  const float* Xi = xn + (size_t)(n*CIN + ii)*NPIX;
  const float* Xj = xn + (size_t)(n*CIN + jj)*NPIX;
  int wv = tid >> 6, lane = tid & 63;
  int col = lane & 31, rg = lane >> 5;
  int w0 = col << 2;
  const int uA = wv, uB = wv + 4;      // uC = 8 handled by wave 3 only
  float accA[9], accB[9], accC[9];
#pragma unroll
  for (int t = 0; t < 9; ++t) { accA[t]=0.0f; accB[t]=0.0f; accC[t]=0.0f; }

  for (int q = 0; q < 4; ++q) {
    __syncthreads();
    for (int t = tid; t < 40*136; t += 256) {
      int r = t / 136, c = t % 136;
      int gh = q*32 - 4 + r, gw = c - 4;
      float v = 0.0f;
      if (gh >= 0 && gh < 128 && gw >= 0 && gw < 128) v = Xi[gh*128 + gw];
      xi_s[t] = v;
    }
    __syncthreads();
    for (int it = 0; it < 16; ++it) {
      int hl = it*2 + rg;              // 0..31 local output row
      int h = q*32 + hl;
      const float4 xjv = *reinterpret_cast<const float4*>(Xj + h*128 + w0);
      float xj[4] = {xjv.x, xjv.y, xjv.z, xjv.w};
      {
        const float* rp = &xi_s[(hl + uA)*136 + w0];
        const float4 a0 = *reinterpret_cast<const float4*>(rp);
        const float4 a1 = *reinterpret_cast<const float4*>(rp + 4);
        const float4 a2 = *reinterpret_cast<const float4*>(rp + 8);
        float xw[12] = {a0.x,a0.y,a0.z,a0.w, a1.x,a1.y,a1.z,a1.w, a2.x,a2.y,a2.z,a2.w};
#pragma unroll
        for (int v = 0; v < 9; ++v)
#pragma unroll
          for (int k = 0; k < 4; ++k) accA[v] += xw[v+k]*xj[k];
      }
      {
        const float* rp = &xi_s[(hl + uB)*136 + w0];
        const float4 a0 = *reinterpret_cast<const float4*>(rp);
        const float4 a1 = *reinterpret_cast<const float4*>(rp + 4);
        const float4 a2 = *reinterpret_cast<const float4*>(rp + 8);
        float xw[12] = {a0.x,a0.y,a0.z,a0.w, a1.x,a1.y,a1.z,a1.w, a2.x,a2.y,a2.z,a2.w};
#pragma unroll
        for (int v = 0; v < 9; ++v)
#pragma unroll
          for (int k = 0; k < 4; ++k) accB[v] += xw[v+k]*xj[k];
      }
      if (wv == 3) {
        const float* rp = &xi_s[(hl + 8)*136 + w0];
        const float4 a0 = *reinterpret_cast<const float4*>(rp);
        const float4 a1 = *reinterpret_cast<const float4*>(rp + 4);
        const float4 a2 = *reinterpret_cast<const float4*>(rp + 8);
        float xw[12] = {a0.x,a0.y,a0.z,a0.w, a1.x,a1.y,a1.z,a1.w, a2.x,a2.y,a2.z,a2.w};
#pragma unroll
        for (int v = 0; v < 9; ++v)
#pragma unroll
          for (int k = 0; k < 4; ++k) accC[v] += xw[v+k]*xj[k];
      }
    }
  }
  float* Rp = ws + OFF_R;
  size_t base  = (((size_t)n*CIN + ii)*CIN + jj)*81;
  size_t baseT = (((size_t)n*CIN + jj)*CIN + ii)*81;
#pragma unroll
  for (int v = 0; v < 9; ++v) { WRED(accA[v]); WRED(accB[v]); }
  if (wv == 3) {
#pragma unroll
    for (int v = 0; v < 9; ++v) { WRED(accC[v]); }
  }
  if (lane == 0) {
#pragma unroll
    for (int v = 0; v < 9; ++v) {
      int uv = uA*9 + v;
      Rp[base + uv] = accA[v];
      Rp[baseT + 80 - uv] = accA[v];
    }
#pragma unroll
    for (int v = 0; v < 9; ++v) {
      int uv = uB*9 + v;
      Rp[base + uv] = accB[v];
      Rp[baseT + 80 - uv] = accB[v];
    }
    if (wv == 3) {
#pragma unroll
      for (int v = 0; v < 9; ++v) {
        int uv = 72 + v;
        Rp[base + uv] = accC[v];
        Rp[baseT + 80 - uv] = accC[v];
      }
    }
  }
}

// ---------------------------------------------------------------------------
// Pm[n, i*25+u*5+v] = sum_{h,w} xnew[n,i,h+u-2,w+v-2]*y[n,h,w] + a_d*d[...]
// ---------------------------------------------------------------------------
__global__ __launch_bounds__(256) void k_pm(const float* __restrict__ xn,
                                            const float* __restrict__ y,
                                            const float* __restrict__ dict,
                                            const float* __restrict__ alpha_d,
                                            const float* __restrict__ regp,
                                            float* __restrict__ ws) {
  __shared__ float xt[20*20];
  __shared__ float red_s[4][25];
  int n = blockIdx.y, i = blockIdx.x, tid = threadIdx.x;
  int py = tid >> 4, px = tid & 15;
  float acc[25];
#pragma unroll
  for (int t = 0; t < 25; ++t) acc[t] = 0.0f;
  const float* Xi = xn + (size_t)(n*CIN + i)*NPIX;
  for (int tile = 0; tile < 64; ++tile) {
    int h0 = (tile >> 3)*16, w0 = (tile & 7)*16;
    __syncthreads();
    for (int t = tid; t < 400; t += 256) {
      int r = t / 20, cc = t % 20;
      int gh = h0 + r - 2, gw = w0 + cc - 2;
      float v = 0.0f;
      if (gh >= 0 && gh < 128 && gw >= 0 && gw < 128) v = Xi[gh*128 + gw];
      xt[t] = v;
    }
    __syncthreads();
    float yv = y[(n*HH + h0 + py)*WW + w0 + px];
#pragma unroll
    for (int u = 0; u < 5; ++u)
#pragma unroll
      for (int v = 0; v < 5; ++v)
        acc[u*5+v] += xt[(py+u)*20 + (px+v)] * yv;
  }
  int lane = tid & 63, wv = tid >> 6;
#pragma unroll
  for (int t = 0; t < 25; ++t) {
    float v = acc[t];
    WRED(v);
    if (lane == 0) red_s[wv][t] = v;
  }
  __syncthreads();
  if (tid < 25) {
    float s = red_s[0][tid] + red_s[1][tid] + red_s[2][tid] + red_s[3][tid];
    float ad = alpha_d[n] * 16384.0f * regp[0] * (1.0f/1600.0f);
    ws[OFF_PM + n*MMAT + i*25 + tid] = s + ad * dict[(n*CIN + i)*25 + tid];
  }
}

// ---------------------------------------------------------------------------
// CG on R directly (no explicit Q). Matvec:
// (A v)[(j,a,c)] = sum_{i,b,d} R[n,i,j,(4+b-a),(4+d-c)] v[(i,b,d)] + reg*v (reg
// folded into R diag? no -- reg added in build_q before; here we must add it:
// Q = R-structure + aI, so Av += a*v. a = alpha_d*16384*reg/1600.
// ---------------------------------------------------------------------------
__global__ __launch_bounds__(256) void k_cg_zero(float* __restrict__ ws) {
  ws[OFF_SC + threadIdx.x] = 0.0f;
}

__global__ __launch_bounds__(256) void k_cg_init(float* __restrict__ ws) {
  int n = blockIdx.y, i = blockIdx.x*256 + threadIdx.x;
  float pval = 0.0f;
  if (i < MMAT) {
    pval = ws[OFF_PM + n*MMAT + i];
    ws[OFF_DV + n*MMAT + i] = 0.0f;
    ws[OFF_RV + n*MMAT + i] = pval;
    ws[OFF_PV + n*MMAT + i] = pval;
  }
  float part = pval*pval;
  WRED(part);
  __shared__ float red[4];
  int lane = threadIdx.x & 63, w = threadIdx.x >> 6;
  if (lane == 0) red[w] = part;
  __syncthreads();
  if (threadIdx.x == 0)
    atomicAdd(&ws[OFF_SC + n*64 + 0], red[0]+red[1]+red[2]+red[3]);
}

// Ap0 = Q p0, pAp0; vin = PV
__global__ __launch_bounds__(256) void k_cg_first(float* __restrict__ ws,
                                                  const float* __restrict__ alpha_d,
                                                  const float* __restrict__ regp) {
  __shared__ float vv[MMAT];
  __shared__ float part[25][66];
  int n = blockIdx.y, j = blockIdx.x, tid = threadIdx.x;
  for (int t = tid; t < MMAT; t += 256) vv[t] = ws[OFF_PV + n*MMAT + t];
  __syncthreads();
  int i = tid & 63, qq = tid >> 6;
  const float* Rij = ws + OFF_R + (((size_t)n*CIN + i)*CIN + j)*81;
  const float* vi = &vv[i*25];
#pragma unroll
  for (int s6 = 0; s6 < 7; ++s6) {
    int ac = qq + 4*s6;
    if (ac < 25) {
      int a = ac/5, c = ac%5;
      float s = 0.0f;
#pragma unroll
      for (int b = 0; b < 5; ++b)
#pragma unroll
        for (int d = 0; d < 5; ++d)
          s += Rij[(4+b-a)*9 + (4+d-c)] * vi[b*5+d];
      part[ac][i] = s;
    }
  }
  __syncthreads();
  float contrib = 0.0f;
  if (tid < 25) {
    float s = 0.0f;
    for (int t = 0; t < 64; ++t) s += part[tid][t];
    float reg = alpha_d[n] * 16384.0f * regp[0] * (1.0f/1600.0f);
    s += reg * vv[j*25 + tid];
    ws[OFF_AP + n*MMAT + j*25 + tid] = s;
    contrib = s * vv[j*25 + tid];
  }
  if (tid < 64) {
    WRED(contrib);
    if (tid == 0) atomicAdd(&ws[OFF_SC + n*64 + 32 + 0], contrib);
  }
}

// beta = rr[it+1]/rr[it]; p' = r + beta p; Ap' = A r + beta Ap; pAp[it+1] += p'.Ap'
__global__ __launch_bounds__(256) void k_cg_step(float* __restrict__ ws, int it,
                                                 const float* __restrict__ alpha_d,
                                                 const float* __restrict__ regp) {
  __shared__ float vv[MMAT];   // r (updated)
  __shared__ float part[25][66];
  int n = blockIdx.y, j = blockIdx.x, tid = threadIdx.x;
  for (int t = tid; t < MMAT; t += 256) vv[t] = ws[OFF_RV + n*MMAT + t];
  __syncthreads();
  int i = tid & 63, qq = tid >> 6;
  const float* Rij = ws + OFF_R + (((size_t)n*CIN + i)*CIN + j)*81;
  const float* vi = &vv[i*25];
#pragma unroll
  for (int s6 = 0; s6 < 7; ++s6) {
    int ac = qq + 4*s6;
    if (ac < 25) {
      int a = ac/5, c = ac%5;
      float s = 0.0f;
#pragma unroll
      for (int b = 0; b < 5; ++b)
#pragma unroll
        for (int d = 0; d < 5; ++d)
          s += Rij[(4+b-a)*9 + (4+d-c)] * vi[b*5+d];
      part[ac][i] = s;
    }
  }
  __syncthreads();
  float contrib = 0.0f;
  if (tid < 25) {
    float s = 0.0f;
    for (int t = 0; t < 64; ++t) s += part[tid][t];
    float reg = alpha_d[n] * 16384.0f * regp[0] * (1.0f/1600.0f);
    s += reg * vv[j*25 + tid];                 // s = (Q r)[j*25+tid]
    float beta = ws[OFF_SC + n*64 + it + 1] / (ws[OFF_SC + n*64 + it] + 1e-30f);
    int idx = n*MMAT + j*25 + tid;
    float pn  = vv[j*25 + tid] + beta * ws[OFF_PV + idx];
    float apn = s + beta * ws[OFF_AP + idx];
    ws[OFF_PV + idx] = pn;
    ws[OFF_AP + idx] = apn;
    contrib = pn * apn;
  }
  if (tid < 64) {
    WRED(contrib);
    if (tid == 0) atomicAdd(&ws[OFF_SC + n*64 + 32 + (it+1)], contrib);
  }
}

// alpha = rr[it]/pAp[it]; d += alpha p; r -= alpha Ap; rr[it+1] += r'.r'
__global__ __launch_bounds__(256) void k_cg_upd(float* __restrict__ ws, int it,
                                                int last, float* __restrict__ out) {
  int n = blockIdx.y, i = blockIdx.x*256 + threadIdx.x;
  float rr  = ws[OFF_SC + n*64 + it];
  float pap = ws[OFF_SC + n*64 + 32 + it];
  float alpha = rr / (pap + 1e-30f);
  float rn = 0.0f;
  if (i < MMAT) {
    float dv = ws[OFF_DV + n*MMAT + i] + alpha * ws[OFF_PV + n*MMAT + i];
    rn = ws[OFF_RV + n*MMAT + i] - alpha * ws[OFF_AP + n*MMAT + i];
    ws[OFF_DV + n*MMAT + i] = dv;
    ws[OFF_RV + n*MMAT + i] = rn;
    if (last) out[4194304 + n*MMAT + i] = dv;
  }
  float part = rn*rn;
  WRED(part);
  __shared__ float red[4];
  int lane = threadIdx.x & 63, w = threadIdx.x >> 6;
  if (lane == 0) red[w] = part;
  __syncthreads();
  if (threadIdx.x == 0)
    atomicAdd(&ws[OFF_SC + n*64 + it + 1], red[0]+red[1]+red[2]+red[3]);
}

// ---------------------------------------------------------------------------
extern "C" void kernel_launch(void* const* d_in, const int* in_sizes, int n_in,
                              void* d_out, int out_size, void* d_ws, size_t ws_size,
                              hipStream_t stream) {
  (void)in_sizes; (void)n_in; (void)out_size; (void)ws_size;
  const float* x    = (const float*)d_in[0];
  const float* dict = (const float*)d_in[1];
  const float* y    = (const float*)d_in[2];
  const float* ax   = (const float*)d_in[3];
  const float* ad   = (const float*)d_in[4];
  const float* regp = (const float*)d_in[5];
  float* out = (float*)d_out;
  float* ws  = (float*)d_ws;   // needs ~6.8 MB

  dim3 b256(256);
  k_sinv<<<dim3(33,4), b256, 0, stream>>>(dict, ax, ws);
  k_e<<<dim3(64,4), b256, 0, stream>>>(x, dict, y, ws);
  k_fft_rows<<<dim3(33,4), b256, 0, stream>>>(ws);
  k_fft_cols<<<dim3(33,4), b256, 0, stream>>>(ws);
  k_ifft_cols<<<dim3(33,4), b256, 0, stream>>>(ws);
  k_ifft_rows<<<dim3(64,4), b256, 0, stream>>>(ws);
  k_xnew<<<dim3(64,4), b256, 0, stream>>>(x, dict, ws, out);
  k_corr<<<dim3(2080,4), b256, 0, stream>>>(out, ws);
  k_pm<<<dim3(64,4), b256, 0, stream>>>(out, y, dict, ad, regp, ws);

  // ---- CG solve (R-direct matvec, fused p/Ap recurrence) ----
  k_cg_zero<<<dim3(1), b256, 0, stream>>>(ws);
  k_cg_init<<<dim3(7,4), b256, 0, stream>>>(ws);
  k_cg_first<<<dim3(64,4), b256, 0, stream>>>(ws, ad, regp);
  for (int it = 0; it < NIT; ++it) {
    k_cg_upd<<<dim3(7,4), b256, 0, stream>>>(ws, it, (it == NIT-1) ? 1 : 0, out);
    if (it < NIT-1)
      k_cg_step<<<dim3(64,4), b256, 0, stream>>>(ws, it, ad, regp);
  }
}